// Round 4
// baseline (226.282 us; speedup 1.0000x reference)
//
#include <hip/hip_runtime.h>
#include <math.h>

// Problem constants (from reference setup_inputs)
#define NB     64      // batch
#define N1V    8192    // obj points per batch
#define NPTS   (NB * N1V)
#define NV     778     // recon / gt verts
#define NVP    780     // padded to multiple of 4
#define NQ     195     // target quads
#define SEG1Q  51      // first 51 quads = 204 permuted targets = PRIOR set
#define NFACE  1538
#define NZ     64
#define NPAR   61
#define NPRIOR 204
#define PPT    8       // obj points per thread (rec/gt roles)
#define BIAS   0.0625f // 2|a||t| <= 0.06 < BIAS -> biased rec partials stay >= 0

// k_fused roles (R0 geometry: 256-thr blocks, 640 total)
#define REC_BLOCKS 256                 // (batch, chunk-of-2048)
#define GT_BLOCKS  256
#define CH_BLOCKS  128                 // (batch, dir)
#define NROLE_BLOCKS (REC_BLOCKS + GT_BLOCKS + CH_BLOCKS)   // 640
#define CMB_BLOCKS 64                  // 64*256 uints over rc/gc words

// ws float4 layout per batch (BATCH_F4 float4s):
//   [0,780)     gt4    (x,y,z,|t|^2)  original order, pads w=1e30
//   [780,1560)  rec4p  (x,y,z,|t|^2+BIAS) PERMUTED (prior first), pads w=1e30
//   [1560,2340) nrm4p  (nx,ny,nz,0)   PERMUTED to match rec4p
#define BATCH_F4 2352                  // padded stride
// float offsets in ws
#define ACC_OFF (NB * BATCH_F4 * 4)   // acc[16]: [2..7] sums, [15] ticket
#define RC_OFF  (ACC_OFF + 16)        // uchar[NPTS/8] rec-cmap bits (1/pt)
#define GC_OFF  (RC_OFF + NPTS / 32)  // uchar[NPTS/8] gt-cmap bits
// acc slots: 2 chamfer, 3 S_cmap, 4 N_cmap, 5 N_gt, 6 N_cons, 7 S_pen

// ---- compile-time prior permutation (pure function of the static index list) ----
static constexpr int PRIOR_LIST[NPRIOR] = {
  697,698,699,700,712,713,714,715,737,738,739,740,741,743,744,745,746,748,749,750,
  753,754,755,756,757,758,759,760,761,762,763,764,765,766,767,768,
  46,47,48,49,164,165,166,167,194,195,223,237,238,280,281,298,301,317,320,323,
  324,325,326,327,328,329,330,331,332,333,340,341,342,343,344,345,346,347,348,349,
  350,351,352,353,354,355,
  356,357,358,359,375,376,386,387,396,397,402,403,413,429,433,434,435,436,437,438,
  439,440,441,442,443,444,452,453,454,455,456,459,460,461,462,463,464,465,466,467,
  468,469,470,471,484,485,486,496,497,506,507,513,514,524,545,546,547,548,549,550,
  551,552,553,555,563,564,565,566,567,570,572,573,574,575,576,577,578,
  580,581,582,583,600,601,602,614,615,624,625,630,631,641,663,664,665,666,667,668,
  670,672,680,681,682,683,684,686,687,688,689,690,691,692,693,694,695,
  73,96,98,99,772,774,775,777
};

struct PermT { unsigned short v[NV]; };
static constexpr PermT make_perm() {
    PermT t{};
    bool mem[NV] = {};
    for (int i = 0; i < NPRIOR; ++i) mem[PRIOR_LIST[i]] = true;
    int a = 0, b = NPRIOR;
    for (int j = 0; j < NV; ++j) {
        if (mem[j]) t.v[a++] = (unsigned short)j;
        else        t.v[b++] = (unsigned short)j;
    }
    return t;
}
__device__ __constant__ PermT c_perm = make_perm();

// ---------------- Kernel 0: permuted target arrays + normals + acc init ------
__global__ __launch_bounds__(256) void k_prep(const float* __restrict__ recon,
                                              const float* __restrict__ gt,
                                              const int* __restrict__ faces,
                                              float4* __restrict__ ws4,
                                              float* __restrict__ acc) {
    int b = blockIdx.x, tid = threadIdx.x;
    if (b == 0 && tid < 16) acc[tid] = 0.0f;
    __shared__ float4 s_r[NV];
    __shared__ float s_vnx[NV], s_vny[NV], s_vnz[NV];

    const float* rb = recon + (size_t)b * NV * 3;
    const float* gb = gt    + (size_t)b * NV * 3;
    float4* gt4   = ws4 + (size_t)b * BATCH_F4;
    float4* rec4p = gt4 + NVP;
    float4* nrm4p = rec4p + NVP;
    for (int j = tid; j < NV; j += 256) {
        float x = rb[3*j], y = rb[3*j+1], z = rb[3*j+2];
        s_r[j] = make_float4(x, y, z, x*x + y*y + z*z + BIAS);
        x = gb[3*j]; y = gb[3*j+1]; z = gb[3*j+2];
        gt4[j] = make_float4(x, y, z, x*x + y*y + z*z);
        s_vnx[j] = 0.0f; s_vny[j] = 0.0f; s_vnz[j] = 0.0f;
    }
    if (tid < 2) gt4[NV + tid] = make_float4(0.f, 0.f, 0.f, 1e30f);
    __syncthreads();
    for (int f = tid; f < NFACE; f += 256) {
        int i0 = faces[3*f], i1 = faces[3*f+1], i2 = faces[3*f+2];
        float4 p0 = s_r[i0], p1 = s_r[i1], p2 = s_r[i2];
        float e1x = p1.x - p0.x, e1y = p1.y - p0.y, e1z = p1.z - p0.z;
        float e2x = p2.x - p0.x, e2y = p2.y - p0.y, e2z = p2.z - p0.z;
        float fx = e1y * e2z - e1z * e2y;
        float fy = e1z * e2x - e1x * e2z;
        float fz = e1x * e2y - e1y * e2x;
        atomicAdd(&s_vnx[i0], fx); atomicAdd(&s_vny[i0], fy); atomicAdd(&s_vnz[i0], fz);
        atomicAdd(&s_vnx[i1], fx); atomicAdd(&s_vny[i1], fy); atomicAdd(&s_vnz[i1], fz);
        atomicAdd(&s_vnx[i2], fx); atomicAdd(&s_vny[i2], fy); atomicAdd(&s_vnz[i2], fz);
    }
    __syncthreads();
    for (int j = tid; j < NVP; j += 256) {
        if (j < NV) {
            int src = c_perm.v[j];
            rec4p[j] = s_r[src];
            float x = s_vnx[src], y = s_vny[src], z = s_vnz[src];
            float inv = 1.0f / (sqrtf(x*x + y*y + z*z) + 1e-12f);
            nrm4p[j] = make_float4(x * inv, y * inv, z * inv, 0.0f);
        } else {
            rec4p[j] = make_float4(0.f, 0.f, 0.f, 1e30f);
            nrm4p[j] = make_float4(0.f, 0.f, 1.f, 0.0f);
        }
    }
}

#define LOAD_PTS(ob)                                                          \
    const float4* ob4 = (const float4*)((ob) + (size_t)tid * 24);             \
    float4 q0 = ob4[0], q1 = ob4[1], q2 = ob4[2],                             \
           q3 = ob4[3], q4 = ob4[4], q5 = ob4[5];                             \
    float px[PPT], py[PPT], pz[PPT];                                          \
    px[0]=q0.x; py[0]=q0.y; pz[0]=q0.z;  px[1]=q0.w; py[1]=q1.x; pz[1]=q1.y;  \
    px[2]=q1.z; py[2]=q1.w; pz[2]=q2.x;  px[3]=q2.y; py[3]=q2.z; pz[3]=q2.w;  \
    px[4]=q3.x; py[4]=q3.y; pz[4]=q3.z;  px[5]=q3.w; py[5]=q4.x; pz[5]=q4.y;  \
    px[6]=q4.z; py[6]=q4.w; pz[6]=q5.x;  px[7]=q5.y; py[7]=q5.z; pz[7]=q5.w;

__device__ __forceinline__ float min3f(float a, float b, float c) {
    return fminf(fminf(a, b), c);
}

// ---- wave-uniform target loads via the scalar pipe (SMEM) ----
typedef float f4s __attribute__((ext_vector_type(4)));

__device__ __forceinline__ f4s sld(unsigned long long base, unsigned int off) {
    f4s r;
    asm volatile("s_load_dwordx4 %0, %1, %2"
                 : "=s"(r) : "s"(base), "s"(off));
    return r;
}
// waits tie the loaded values so uses cannot be hoisted above the wait
#define SWAIT8(A0,A1,A2,A3,B0,B1,B2,B3)                                       \
    asm volatile("s_waitcnt lgkmcnt(0)"                                       \
                 : "+s"(A0),"+s"(A1),"+s"(A2),"+s"(A3),                       \
                   "+s"(B0),"+s"(B1),"+s"(B2),"+s"(B3))
#define SWAIT4(A0,A1,A2,A3)                                                   \
    asm volatile("s_waitcnt lgkmcnt(0)"                                       \
                 : "+s"(A0),"+s"(A1),"+s"(A2),"+s"(A3))

// distance eval for one quad (4 targets in SGPR f4s) against PPT points
#define QUAD_MINQ(T0,T1,T2,T3,JQ)                                             \
    _Pragma("unroll")                                                         \
    for (int i = 0; i < PPT; ++i) {                                           \
        float d0 = fmaf(nax[i],(T0)[0], fmaf(nay[i],(T0)[1], fmaf(naz[i],(T0)[2],(T0)[3]))); \
        float d1 = fmaf(nax[i],(T1)[0], fmaf(nay[i],(T1)[1], fmaf(naz[i],(T1)[2],(T1)[3]))); \
        float d2 = fmaf(nax[i],(T2)[0], fmaf(nay[i],(T2)[1], fmaf(naz[i],(T2)[2],(T2)[3]))); \
        float d3 = fmaf(nax[i],(T3)[0], fmaf(nay[i],(T3)[1], fmaf(naz[i],(T3)[2],(T3)[3]))); \
        float u  = min3f(d0, d1, d2);                                         \
        float mn = min3f(u, d3, m[i]);                                        \
        q[i] = (mn < m[i]) ? (JQ) : q[i];                                     \
        m[i] = mn;                                                            \
    }

#define QUAD_MIN(T0,T1,T2,T3)                                                 \
    _Pragma("unroll")                                                         \
    for (int i = 0; i < PPT; ++i) {                                           \
        float d0 = fmaf(nax[i],(T0)[0], fmaf(nay[i],(T0)[1], fmaf(naz[i],(T0)[2],(T0)[3]))); \
        float d1 = fmaf(nax[i],(T1)[0], fmaf(nay[i],(T1)[1], fmaf(naz[i],(T1)[2],(T1)[3]))); \
        float d2 = fmaf(nax[i],(T2)[0], fmaf(nay[i],(T2)[1], fmaf(naz[i],(T2)[2],(T2)[3]))); \
        float d3 = fmaf(nax[i],(T3)[0], fmaf(nay[i],(T3)[1], fmaf(naz[i],(T3)[2],(T3)[3]))); \
        float u  = min3f(d0, d1, d2);                                         \
        m[i] = min3f(u, d3, m[i]);                                            \
    }

#define LOAD_PAIR(BASE,OFF)                                                   \
    f4s a0 = sld(BASE,(OFF)),      a1 = sld(BASE,(OFF)+16),                   \
        a2 = sld(BASE,(OFF)+32),   a3 = sld(BASE,(OFF)+48);                   \
    f4s b0 = sld(BASE,(OFF)+64),   b1 = sld(BASE,(OFF)+80),                   \
        b2 = sld(BASE,(OFF)+96),   b3 = sld(BASE,(OFF)+112);                  \
    SWAIT8(a0,a1,a2,a3,b0,b1,b2,b3);

// ---------------- Fused role kernel (SGPR target stream, no LDS staging) ----
// [0,256): rec quad-argmin + full epilogue  [256,512): gt min + gc bits
// [512,640): chamfer
__global__ __launch_bounds__(256) void k_fused(const float* __restrict__ obj,
                                               const float4* __restrict__ ws4,
                                               float* __restrict__ acc,
                                               unsigned char* __restrict__ rcA,
                                               unsigned char* __restrict__ gcA) {
    __shared__ float s_red[3];
    int tid = threadIdx.x;
    int blk = blockIdx.x;

    if (blk < REC_BLOCKS) {
        // ============ REC ROLE: scan + inline epilogue ============
        int b = blk >> 2, chunk = blk & 3;
        const float4* base  = ws4 + (size_t)b * BATCH_F4;
        const float4* rec4p = base + NVP;
        const float4* nrm4p = base + 2 * NVP;
        unsigned long long recA = (unsigned long long)rec4p;
        if (tid < 3) s_red[tid] = 0.0f;
        __syncthreads();

        const float* ob = obj + ((size_t)b * N1V + (size_t)chunk * 2048) * 3;
        LOAD_PTS(ob)
        float nax[PPT], nay[PPT], naz[PPT], m[PPT];
        int q[PPT];
#pragma unroll
        for (int i = 0; i < PPT; ++i) {
            nax[i] = -2.0f * px[i]; nay[i] = -2.0f * py[i]; naz[i] = -2.0f * pz[i];
            m[i] = 3.4e38f; q[i] = 0;
        }
        float mp[PPT];
        // prior segment: quads 0..50  (25 pairs + 1 single)
#pragma unroll 1
        for (int p = 0; p < 25; ++p) {
            unsigned int off = (unsigned int)p * 128u;
            LOAD_PAIR(recA, off)
            QUAD_MINQ(a0,a1,a2,a3, 2*p)
            QUAD_MINQ(b0,b1,b2,b3, 2*p+1)
        }
        {
            unsigned int off = 50u * 64u;
            f4s a0 = sld(recA,off), a1 = sld(recA,off+16),
                a2 = sld(recA,off+32), a3 = sld(recA,off+48);
            SWAIT4(a0,a1,a2,a3);
            QUAD_MINQ(a0,a1,a2,a3, 50)
        }
#pragma unroll
        for (int i = 0; i < PPT; ++i) mp[i] = m[i];   // prior min snapshot
        // remaining segment: quads 51..194  (72 pairs)
#pragma unroll 1
        for (int p = 0; p < 72; ++p) {
            unsigned int off = (51u + 2u*(unsigned int)p) * 64u;
            LOAD_PAIR(recA, off)
            QUAD_MINQ(a0,a1,a2,a3, 51 + 2*p)
            QUAD_MINQ(b0,b1,b2,b3, 52 + 2*p)
        }
        // ---- inline epilogue (winning-quad re-eval from GLOBAL, L2-resident) ----
        float lS_cmap = 0.0f, lN_cmap = 0.0f, lS_pen = 0.0f;
        unsigned int rcbits = 0;
#pragma unroll
        for (int i = 0; i < PPT; ++i) {
            float a2v = px[i]*px[i] + py[i]*py[i] + pz[i]*pz[i];
            float drec = fmaxf(a2v + (m[i]  - BIAS), 0.0f);
            float dpri = fmaxf(a2v + (mp[i] - BIAS), 0.0f);
            bool cm = drec < 1e-4f;
            bool rc = sqrtf(drec) < 0.005f;
            if (cm) { lS_cmap += dpri; lN_cmap += 1.0f; }
            if (rc) rcbits |= (1u << i);
            int jr = 4 * q[i];
            float4 t0 = rec4p[jr], t1 = rec4p[jr+1], t2 = rec4p[jr+2], t3 = rec4p[jr+3];
            float d0 = fmaf(nax[i], t0.x, fmaf(nay[i], t0.y, fmaf(naz[i], t0.z, t0.w)));
            float d1 = fmaf(nax[i], t1.x, fmaf(nay[i], t1.y, fmaf(naz[i], t1.z, t1.w)));
            float d2 = fmaf(nax[i], t2.x, fmaf(nay[i], t2.y, fmaf(naz[i], t2.z, t2.w)));
            float d3 = fmaf(nax[i], t3.x, fmaf(nay[i], t3.y, fmaf(naz[i], t3.z, t3.w)));
            float mmin = fminf(fminf(d0, d1), fminf(d2, d3));
            int off = (d0 == mmin) ? 0 : ((d1 == mmin) ? 1 : ((d2 == mmin) ? 2 : 3));
            int jstar = jr + off;
            float4 tS = rec4p[jstar];
            float4 nr = nrm4p[jstar];
            float ddot = (tS.x - px[i]) * nr.x + (tS.y - py[i]) * nr.y
                       + (tS.z - pz[i]) * nr.z;
            if (ddot > 0.0f) lS_pen += drec;
        }
        rcA[(size_t)blk * 256 + tid] = (unsigned char)rcbits;
        atomicAdd(&s_red[0], lS_cmap);
        atomicAdd(&s_red[1], lN_cmap);
        atomicAdd(&s_red[2], lS_pen);
        __syncthreads();
        if (tid == 0) atomicAdd(&acc[3], s_red[0]);
        if (tid == 1) atomicAdd(&acc[4], s_red[1]);
        if (tid == 2) atomicAdd(&acc[7], s_red[2]);
        return;
    }

    if (blk < REC_BLOCKS + GT_BLOCKS) {
        // ============ GT ROLE: min scan + gc bits ============
        int r = blk - REC_BLOCKS;
        int b = r >> 2, chunk = r & 3;
        unsigned long long gtA = (unsigned long long)(ws4 + (size_t)b * BATCH_F4);
        if (tid == 0) s_red[0] = 0.0f;
        __syncthreads();

        const float* ob = obj + ((size_t)b * N1V + (size_t)chunk * 2048) * 3;
        LOAD_PTS(ob)
        float nax[PPT], nay[PPT], naz[PPT], m[PPT];
#pragma unroll
        for (int i = 0; i < PPT; ++i) {
            nax[i] = -2.0f * px[i]; nay[i] = -2.0f * py[i]; naz[i] = -2.0f * pz[i];
            m[i] = 3.4e38f;
        }
        // 195 quads = 97 pairs + 1 single
#pragma unroll 1
        for (int p = 0; p < 97; ++p) {
            unsigned int off = (unsigned int)p * 128u;
            LOAD_PAIR(gtA, off)
            QUAD_MIN(a0,a1,a2,a3)
            QUAD_MIN(b0,b1,b2,b3)
        }
        {
            unsigned int off = 194u * 64u;
            f4s a0 = sld(gtA,off), a1 = sld(gtA,off+16),
                a2 = sld(gtA,off+32), a3 = sld(gtA,off+48);
            SWAIT4(a0,a1,a2,a3);
            QUAD_MIN(a0,a1,a2,a3)
        }
        float lN_gt = 0.0f;
        unsigned int gcbits = 0;
#pragma unroll
        for (int i = 0; i < PPT; ++i) {
            float a2v = px[i]*px[i] + py[i]*py[i] + pz[i]*pz[i];
            float dgt = fmaxf(a2v + m[i], 0.0f);
            if (sqrtf(dgt) < 0.005f) { lN_gt += 1.0f; gcbits |= (1u << i); }
        }
        gcA[(size_t)r * 256 + tid] = (unsigned char)gcbits;
        atomicAdd(&s_red[0], lN_gt);
        __syncthreads();
        if (tid == 0) atomicAdd(&acc[5], s_red[0]);
        return;
    }

    // ============ CHAMFER ROLE (4 sources/thread) ============
    {
        int c   = blk - (REC_BLOCKS + GT_BLOCKS);
        int b   = c >> 1;
        int dir = c & 1;           // 0: rec->gt, 1: gt->rec
        const float4* base = ws4 + (size_t)b * BATCH_F4;
        const float4* srcv = dir ? base : (base + NVP);   // gt4 : rec4p
        const float4* tgtv = dir ? (base + NVP) : base;   // rec4p : gt4
        unsigned long long tgA = (unsigned long long)tgtv;
        if (tid == 0) s_red[0] = 0.0f;
        __syncthreads();

        const int CPT = 4;
        float nax[CPT], nay[CPT], naz[CPT], sa2[CPT], m[CPT];
        bool valid[CPT];
#pragma unroll
        for (int k = 0; k < CPT; ++k) {
            int p = tid + 256 * k;
            valid[k] = (p < NV);
            float4 s = srcv[valid[k] ? p : 0];
            nax[k] = -2.0f * s.x; nay[k] = -2.0f * s.y; naz[k] = -2.0f * s.z;
            sa2[k] = s.w;                 // one of src/tgt carries +BIAS
            m[k] = 3.4e38f;
        }
#pragma unroll 1
        for (int p = 0; p < 97; ++p) {
            unsigned int off = (unsigned int)p * 128u;
            LOAD_PAIR(tgA, off)
#pragma unroll
            for (int k = 0; k < CPT; ++k) {
                float d0 = fmaf(nax[k],a0[0], fmaf(nay[k],a0[1], fmaf(naz[k],a0[2],a0[3])));
                float d1 = fmaf(nax[k],a1[0], fmaf(nay[k],a1[1], fmaf(naz[k],a1[2],a1[3])));
                float d2 = fmaf(nax[k],a2[0], fmaf(nay[k],a2[1], fmaf(naz[k],a2[2],a2[3])));
                float d3 = fmaf(nax[k],a3[0], fmaf(nay[k],a3[1], fmaf(naz[k],a3[2],a3[3])));
                float u = min3f(d0, d1, d2);
                m[k] = min3f(u, d3, m[k]);
                float e0 = fmaf(nax[k],b0[0], fmaf(nay[k],b0[1], fmaf(naz[k],b0[2],b0[3])));
                float e1 = fmaf(nax[k],b1[0], fmaf(nay[k],b1[1], fmaf(naz[k],b1[2],b1[3])));
                float e2 = fmaf(nax[k],b2[0], fmaf(nay[k],b2[1], fmaf(naz[k],b2[2],b2[3])));
                float e3 = fmaf(nax[k],b3[0], fmaf(nay[k],b3[1], fmaf(naz[k],b3[2],b3[3])));
                float v = min3f(e0, e1, e2);
                m[k] = min3f(v, e3, m[k]);
            }
        }
        {
            unsigned int off = 194u * 64u;
            f4s a0 = sld(tgA,off), a1 = sld(tgA,off+16),
                a2 = sld(tgA,off+32), a3 = sld(tgA,off+48);
            SWAIT4(a0,a1,a2,a3);
#pragma unroll
            for (int k = 0; k < CPT; ++k) {
                float d0 = fmaf(nax[k],a0[0], fmaf(nay[k],a0[1], fmaf(naz[k],a0[2],a0[3])));
                float d1 = fmaf(nax[k],a1[0], fmaf(nay[k],a1[1], fmaf(naz[k],a1[2],a1[3])));
                float d2 = fmaf(nax[k],a2[0], fmaf(nay[k],a2[1], fmaf(naz[k],a2[2],a2[3])));
                float d3 = fmaf(nax[k],a3[0], fmaf(nay[k],a3[1], fmaf(naz[k],a3[2],a3[3])));
                float u = min3f(d0, d1, d2);
                m[k] = min3f(u, d3, m[k]);
            }
        }
        float local = 0.0f;
#pragma unroll
        for (int k = 0; k < CPT; ++k)
            if (valid[k]) local += fmaxf(sa2[k] + m[k] - BIAS, 0.0f);
        atomicAdd(&s_red[0], local);
        __syncthreads();
        if (tid == 0) atomicAdd(&acc[2], s_red[0]);
    }
}

// ---------------- Combine (popcount rc&gc) + finalize (ticket) ----------------
__global__ __launch_bounds__(256) void k_combine(float* __restrict__ acc,
                                                 const unsigned int* __restrict__ rcW,
                                                 const unsigned int* __restrict__ gcW,
                                                 const float* __restrict__ mean,
                                                 const float* __restrict__ log_var,
                                                 const float* __restrict__ rp,
                                                 const float* __restrict__ xp,
                                                 float* __restrict__ out) {
    int blk = blockIdx.x, tid = threadIdx.x;
    __shared__ float s_red[2];
    __shared__ unsigned int s_ticket;
    if (tid < 2) s_red[tid] = 0.0f;
    __syncthreads();
    int idx = blk * 256 + tid;                    // 16384 uints = NPTS/8 bytes
    unsigned int rc = rcW[idx], gc = gcW[idx];
    float cnt = (float)__popc(rc & gc);
    atomicAdd(&s_red[0], cnt);
    __syncthreads();
    if (tid == 0) atomicAdd(&acc[6], s_red[0]);
    __threadfence();
    if (tid == 0) s_ticket = atomicAdd((unsigned int*)&acc[15], 1u);
    __syncthreads();

    if (s_ticket == CMB_BLOCKS - 1) {
        if (tid < 2) s_red[tid] = 0.0f;
        __syncthreads();
        float s_param = 0.0f, s_kld = 0.0f;
        for (int i = tid; i < NB * NPAR; i += 256) {
            float d = rp[i] - xp[i];
            s_param += d * d;
        }
        for (int i = tid; i < NB * NZ; i += 256) {
            float m = mean[i], lv = log_var[i];
            s_kld += 1.0f + lv - m * m - expf(lv);
        }
        atomicAdd(&s_red[0], s_param);
        atomicAdd(&s_red[1], s_kld);
        __syncthreads();
        if (tid == 0) {
            const float fB = 64.0f;
            float a2v = atomicAdd(&acc[2], 0.0f);
            float a3  = atomicAdd(&acc[3], 0.0f);
            float a4  = atomicAdd(&acc[4], 0.0f);
            float a5  = atomicAdd(&acc[5], 0.0f);
            float a6  = atomicAdd(&acc[6], 0.0f);
            float a7  = atomicAdd(&acc[7], 0.0f);
            float param_loss  = s_red[0] / fB;
            float KLD         = -0.5f * s_red[1] / fB * 10.0f;
            float recon_loss  = a2v / fB;
            float cmap_loss   = 3000.0f * a3 / (fB * a4);
            float consistency = -5.0f * a6 / (a5 + 0.0001f);
            float penetr      = 100.0f * a7 / fB;
            out[0] = (recon_loss + KLD) + 0.1f * param_loss + 1000.0f * cmap_loss
                   + 10.0f * consistency + 10.0f * penetr;
        }
    }
}

extern "C" void kernel_launch(void* const* d_in, const int* in_sizes, int n_in,
                              void* d_out, int out_size, void* d_ws, size_t ws_size,
                              hipStream_t stream) {
    (void)in_sizes; (void)n_in; (void)out_size; (void)ws_size;
    const float* obj     = (const float*)d_in[0];
    const float* recon   = (const float*)d_in[1];
    const float* gt      = (const float*)d_in[2];
    const float* mean    = (const float*)d_in[3];
    const float* log_var = (const float*)d_in[4];
    const float* rp      = (const float*)d_in[5];
    const float* xp      = (const float*)d_in[6];
    const int*   faces   = (const int*)d_in[7];
    float* acc  = (float*)d_ws + ACC_OFF;
    float4* ws4 = (float4*)d_ws;
    unsigned char* rcA = (unsigned char*)((float*)d_ws + RC_OFF);
    unsigned char* gcA = (unsigned char*)((float*)d_ws + GC_OFF);
    float* out  = (float*)d_out;

    k_prep   <<<NB,           256, 0, stream>>>(recon, gt, faces, ws4, acc);
    k_fused  <<<NROLE_BLOCKS, 256, 0, stream>>>(obj, ws4, acc, rcA, gcA);
    k_combine<<<CMB_BLOCKS,   256, 0, stream>>>(acc, (const unsigned int*)rcA,
                                                (const unsigned int*)gcA,
                                                mean, log_var, rp, xp, out);
}

// Round 6
// 206.692 us; speedup vs baseline: 1.0948x; 1.0948x over previous
//
#include <hip/hip_runtime.h>
#include <math.h>

// Problem constants (from reference setup_inputs)
#define NB     64      // batch
#define N1V    8192    // obj points per batch
#define NPTS   (NB * N1V)
#define NV     778     // recon / gt verts
#define NVP    780     // padded to multiple of 4
#define NQ     195     // target quads
#define SEG1Q  51      // first 51 quads = 204 permuted targets = PRIOR set
#define NFACE  1538
#define NZ     64
#define NPAR   61
#define NPRIOR 204
#define PPT    8       // obj points per thread (rec/gt roles)
#define BIAS   0.0625f // 2|a||t| <= 0.06 < BIAS -> biased rec partials stay >= 0

// k_fused roles (R0 geometry: 256-thr blocks, 640 total)
#define REC_BLOCKS 256                 // (batch, chunk-of-2048)
#define GT_BLOCKS  256
#define CH_BLOCKS  128                 // (batch, dir)
#define NROLE_BLOCKS (REC_BLOCKS + GT_BLOCKS + CH_BLOCKS)   // 640

// k_prep: 3 roles x 64 batches = 192 blocks
#define PREP_BLOCKS 192

// ws float4 layout per batch (BATCH_F4 float4s):
//   [0,780)     gt4    (x,y,z,|t|^2)  original order, pads w=1e30
//   [780,1560)  rec4p  (x,y,z,|t|^2+BIAS) PERMUTED (prior first), pads w=1e30
//   [1560,2340) nrm4p  (nx,ny,nz,0)   RAW face-normal sums, PERMUTED (sign-only use)
#define BATCH_F4 2352                  // padded stride
// float offsets in ws
#define ACC_OFF (NB * BATCH_F4 * 4)   // acc[16]: [2..7] sums, [15] ticket
#define RC_OFF  (ACC_OFF + 16)        // uchar[NPTS/8] rec-cmap bits (1/pt)
#define GC_OFF  (RC_OFF + NPTS / 32)  // uchar[NPTS/8] gt-cmap bits
// acc slots: 2 chamfer, 3 S_cmap, 4 N_cmap, 5 N_gt, 7 S_pen, 15 ticket

// ---- compile-time prior permutation (pure function of the static index list) ----
static constexpr int PRIOR_LIST[NPRIOR] = {
  697,698,699,700,712,713,714,715,737,738,739,740,741,743,744,745,746,748,749,750,
  753,754,755,756,757,758,759,760,761,762,763,764,765,766,767,768,
  46,47,48,49,164,165,166,167,194,195,223,237,238,280,281,298,301,317,320,323,
  324,325,326,327,328,329,330,331,332,333,340,341,342,343,344,345,346,347,348,349,
  350,351,352,353,354,355,
  356,357,358,359,375,376,386,387,396,397,402,403,413,429,433,434,435,436,437,438,
  439,440,441,442,443,444,452,453,454,455,456,459,460,461,462,463,464,465,466,467,
  468,469,470,471,484,485,486,496,497,506,507,513,514,524,545,546,547,548,549,550,
  551,552,553,555,563,564,565,566,567,570,572,573,574,575,576,577,578,
  580,581,582,583,600,601,602,614,615,624,625,630,631,641,663,664,665,666,667,668,
  670,672,680,681,682,683,684,686,687,688,689,690,691,692,693,694,695,
  73,96,98,99,772,774,775,777
};

struct PermT { unsigned short v[NV]; };
static constexpr PermT make_perm() {
    PermT t{};
    bool mem[NV] = {};
    for (int i = 0; i < NPRIOR; ++i) mem[PRIOR_LIST[i]] = true;
    int a = 0, b = NPRIOR;
    for (int j = 0; j < NV; ++j) {
        if (mem[j]) t.v[a++] = (unsigned short)j;
        else        t.v[b++] = (unsigned short)j;
    }
    return t;
}
__device__ __constant__ PermT c_perm = make_perm();

// ---------------- Kernel 0: prep, 3 parallel roles per batch ------
// role 0: gt4 stream (+acc init on b==0)
// role 1: rec4p permuted stream
// role 2: face normals (RAW sums, no normalize) -> nrm4p permuted
__global__ __launch_bounds__(256) void k_prep(const float* __restrict__ recon,
                                              const float* __restrict__ gt,
                                              const int* __restrict__ faces,
                                              float4* __restrict__ ws4,
                                              float* __restrict__ acc) {
    int blk = blockIdx.x, tid = threadIdx.x;
    int b = blk & 63, role = blk >> 6;
    float4* gt4   = ws4 + (size_t)b * BATCH_F4;
    float4* rec4p = gt4 + NVP;
    float4* nrm4p = rec4p + NVP;

    if (role == 0) {
        // ---- GT stream ----
        if (b == 0 && tid < 16) acc[tid] = 0.0f;
        const float* gb = gt + (size_t)b * NV * 3;
        for (int j = tid; j < NV; j += 256) {
            float x = gb[3*j], y = gb[3*j+1], z = gb[3*j+2];
            gt4[j] = make_float4(x, y, z, x*x + y*y + z*z);
        }
        if (tid < 2) gt4[NV + tid] = make_float4(0.f, 0.f, 0.f, 1e30f);
        return;
    }

    if (role == 1) {
        // ---- REC permuted stream (gather via constexpr perm) ----
        const float* rb = recon + (size_t)b * NV * 3;
        for (int j = tid; j < NVP; j += 256) {
            if (j < NV) {
                int src = c_perm.v[j];
                float x = rb[3*src], y = rb[3*src+1], z = rb[3*src+2];
                rec4p[j] = make_float4(x, y, z, x*x + y*y + z*z + BIAS);
            } else {
                rec4p[j] = make_float4(0.f, 0.f, 0.f, 1e30f);
            }
        }
        return;
    }

    // ---- role 2: face normals (raw sums; only the SIGN of dot(nn_v-p, n) is used) ----
    {
        __shared__ float s_x[NV], s_y[NV], s_z[NV];
        __shared__ float s_vnx[NV], s_vny[NV], s_vnz[NV];
        const float* rb = recon + (size_t)b * NV * 3;
        for (int j = tid; j < NV; j += 256) {
            s_x[j] = rb[3*j]; s_y[j] = rb[3*j+1]; s_z[j] = rb[3*j+2];
            s_vnx[j] = 0.0f; s_vny[j] = 0.0f; s_vnz[j] = 0.0f;
        }
        __syncthreads();
        for (int f = tid; f < NFACE; f += 256) {
            int i0 = faces[3*f], i1 = faces[3*f+1], i2 = faces[3*f+2];
            float p0x = s_x[i0], p0y = s_y[i0], p0z = s_z[i0];
            float e1x = s_x[i1] - p0x, e1y = s_y[i1] - p0y, e1z = s_z[i1] - p0z;
            float e2x = s_x[i2] - p0x, e2y = s_y[i2] - p0y, e2z = s_z[i2] - p0z;
            float fx = e1y * e2z - e1z * e2y;
            float fy = e1z * e2x - e1x * e2z;
            float fz = e1x * e2y - e1y * e2x;
            atomicAdd(&s_vnx[i0], fx); atomicAdd(&s_vny[i0], fy); atomicAdd(&s_vnz[i0], fz);
            atomicAdd(&s_vnx[i1], fx); atomicAdd(&s_vny[i1], fy); atomicAdd(&s_vnz[i1], fz);
            atomicAdd(&s_vnx[i2], fx); atomicAdd(&s_vny[i2], fy); atomicAdd(&s_vnz[i2], fz);
        }
        __syncthreads();
        for (int j = tid; j < NVP; j += 256) {
            if (j < NV) {
                int src = c_perm.v[j];
                nrm4p[j] = make_float4(s_vnx[src], s_vny[src], s_vnz[src], 0.0f);
            } else {
                nrm4p[j] = make_float4(0.f, 0.f, 1.f, 0.0f);
            }
        }
    }
}

#define LOAD_PTS(ob)                                                          \
    const float4* ob4 = (const float4*)((ob) + (size_t)tid * 24);             \
    float4 q0 = ob4[0], q1 = ob4[1], q2 = ob4[2],                             \
           q3 = ob4[3], q4 = ob4[4], q5 = ob4[5];                             \
    float px[PPT], py[PPT], pz[PPT];                                          \
    px[0]=q0.x; py[0]=q0.y; pz[0]=q0.z;  px[1]=q0.w; py[1]=q1.x; pz[1]=q1.y;  \
    px[2]=q1.z; py[2]=q1.w; pz[2]=q2.x;  px[3]=q2.y; py[3]=q2.z; pz[3]=q2.w;  \
    px[4]=q3.x; py[4]=q3.y; pz[4]=q3.z;  px[5]=q3.w; py[5]=q4.x; pz[5]=q4.y;  \
    px[6]=q4.z; py[6]=q4.w; pz[6]=q5.x;  px[7]=q5.y; py[7]=q5.z; pz[7]=q5.w;

__device__ __forceinline__ float min3f(float a, float b, float c) {
    return fminf(fminf(a, b), c);
}

// ---------------- Fused role kernel + ticket-gated finalize tail ----
// [0,256): rec quad-argmin + epilogue  [256,512): gt min + gc bits
// [512,640): chamfer.  Last block to finish: combine + final loss.
__global__ __launch_bounds__(256, 3) void k_fused(const float* __restrict__ obj,
                                                  const float4* __restrict__ ws4,
                                                  float* __restrict__ acc,
                                                  unsigned char* __restrict__ rcA,
                                                  unsigned char* __restrict__ gcA,
                                                  const float* __restrict__ mean,
                                                  const float* __restrict__ log_var,
                                                  const float* __restrict__ rp,
                                                  const float* __restrict__ xp,
                                                  float* __restrict__ out) {
    __shared__ float4 s_t[NVP];
    __shared__ float s_red[8];
    __shared__ unsigned int s_tk;
    int tid = threadIdx.x;
    int blk = blockIdx.x;

    if (blk < REC_BLOCKS) {
        // ============ REC ROLE: scan + inline epilogue ============
        int b = blk >> 2, chunk = blk & 3;
        const float4* base = ws4 + (size_t)b * BATCH_F4;
        const float4* rec4p = base + NVP;
        const float4* nrm4p = base + 2 * NVP;
        for (int j = tid; j < NVP; j += 256) s_t[j] = rec4p[j];
        if (tid < 3) s_red[tid] = 0.0f;
        __syncthreads();

        const float* ob = obj + ((size_t)b * N1V + (size_t)chunk * 2048) * 3;
        LOAD_PTS(ob)
        float nax[PPT], nay[PPT], naz[PPT], m[PPT];
        int q[PPT];
#pragma unroll
        for (int i = 0; i < PPT; ++i) {
            nax[i] = -2.0f * px[i]; nay[i] = -2.0f * py[i]; naz[i] = -2.0f * pz[i];
            m[i] = 3.4e38f; q[i] = 0;
        }
        float mp[PPT];
#pragma unroll 2
        for (int jq = 0; jq < SEG1Q; ++jq) {
            int j = 4 * jq;
            float4 t0 = s_t[j], t1 = s_t[j+1], t2 = s_t[j+2], t3 = s_t[j+3];
#pragma unroll
            for (int i = 0; i < PPT; ++i) {
                float d0 = fmaf(nax[i], t0.x, fmaf(nay[i], t0.y, fmaf(naz[i], t0.z, t0.w)));
                float d1 = fmaf(nax[i], t1.x, fmaf(nay[i], t1.y, fmaf(naz[i], t1.z, t1.w)));
                float d2 = fmaf(nax[i], t2.x, fmaf(nay[i], t2.y, fmaf(naz[i], t2.z, t2.w)));
                float d3 = fmaf(nax[i], t3.x, fmaf(nay[i], t3.y, fmaf(naz[i], t3.z, t3.w)));
                float u  = min3f(d0, d1, d2);
                float mn = min3f(u, d3, m[i]);
                q[i] = (mn < m[i]) ? jq : q[i];
                m[i] = mn;
            }
        }
#pragma unroll
        for (int i = 0; i < PPT; ++i) mp[i] = m[i];   // prior min snapshot
#pragma unroll 2
        for (int jq = SEG1Q; jq < NQ; ++jq) {
            int j = 4 * jq;
            float4 t0 = s_t[j], t1 = s_t[j+1], t2 = s_t[j+2], t3 = s_t[j+3];
#pragma unroll
            for (int i = 0; i < PPT; ++i) {
                float d0 = fmaf(nax[i], t0.x, fmaf(nay[i], t0.y, fmaf(naz[i], t0.z, t0.w)));
                float d1 = fmaf(nax[i], t1.x, fmaf(nay[i], t1.y, fmaf(naz[i], t1.z, t1.w)));
                float d2 = fmaf(nax[i], t2.x, fmaf(nay[i], t2.y, fmaf(naz[i], t2.z, t2.w)));
                float d3 = fmaf(nax[i], t3.x, fmaf(nay[i], t3.y, fmaf(naz[i], t3.z, t3.w)));
                float u  = min3f(d0, d1, d2);
                float mn = min3f(u, d3, m[i]);
                q[i] = (mn < m[i]) ? jq : q[i];
                m[i] = mn;
            }
        }
        // ---- inline epilogue (winning-quad re-eval from LDS, bit-identical fma chain) ----
        float lS_cmap = 0.0f, lN_cmap = 0.0f, lS_pen = 0.0f;
        unsigned int rcbits = 0;
#pragma unroll
        for (int i = 0; i < PPT; ++i) {
            float a2 = px[i]*px[i] + py[i]*py[i] + pz[i]*pz[i];
            float drec = fmaxf(a2 + (m[i]  - BIAS), 0.0f);
            float dpri = fmaxf(a2 + (mp[i] - BIAS), 0.0f);
            bool cm = drec < 1e-4f;
            bool rc = sqrtf(drec) < 0.005f;
            if (cm) { lS_cmap += dpri; lN_cmap += 1.0f; }
            if (rc) rcbits |= (1u << i);
            int jr = 4 * q[i];
            float4 t0 = s_t[jr], t1 = s_t[jr+1], t2 = s_t[jr+2], t3 = s_t[jr+3];
            float d0 = fmaf(nax[i], t0.x, fmaf(nay[i], t0.y, fmaf(naz[i], t0.z, t0.w)));
            float d1 = fmaf(nax[i], t1.x, fmaf(nay[i], t1.y, fmaf(naz[i], t1.z, t1.w)));
            float d2 = fmaf(nax[i], t2.x, fmaf(nay[i], t2.y, fmaf(naz[i], t2.z, t2.w)));
            float d3 = fmaf(nax[i], t3.x, fmaf(nay[i], t3.y, fmaf(naz[i], t3.z, t3.w)));
            float mmin = fminf(fminf(d0, d1), fminf(d2, d3));
            int off = (d0 == mmin) ? 0 : ((d1 == mmin) ? 1 : ((d2 == mmin) ? 2 : 3));
            int jstar = jr + off;
            float4 tS = s_t[jstar];
            float4 nr = nrm4p[jstar];   // RAW normal sum: only sign of ddot matters
            float ddot = (tS.x - px[i]) * nr.x + (tS.y - py[i]) * nr.y
                       + (tS.z - pz[i]) * nr.z;
            if (ddot > 0.0f) lS_pen += drec;
        }
        rcA[(size_t)blk * 256 + tid] = (unsigned char)rcbits;
        atomicAdd(&s_red[0], lS_cmap);
        atomicAdd(&s_red[1], lN_cmap);
        atomicAdd(&s_red[2], lS_pen);
        __syncthreads();
        if (tid == 0) atomicAdd(&acc[3], s_red[0]);
        if (tid == 1) atomicAdd(&acc[4], s_red[1]);
        if (tid == 2) atomicAdd(&acc[7], s_red[2]);
    } else if (blk < REC_BLOCKS + GT_BLOCKS) {
        // ============ GT ROLE: min scan + gc bits ============
        int r = blk - REC_BLOCKS;
        int b = r >> 2, chunk = r & 3;
        const float4* gt4v = ws4 + (size_t)b * BATCH_F4;
        for (int j = tid; j < NVP; j += 256) s_t[j] = gt4v[j];
        if (tid == 0) s_red[0] = 0.0f;
        __syncthreads();

        const float* ob = obj + ((size_t)b * N1V + (size_t)chunk * 2048) * 3;
        LOAD_PTS(ob)
        float nax[PPT], nay[PPT], naz[PPT], mgt[PPT];
#pragma unroll
        for (int i = 0; i < PPT; ++i) {
            nax[i] = -2.0f * px[i]; nay[i] = -2.0f * py[i]; naz[i] = -2.0f * pz[i];
            mgt[i] = 3.4e38f;
        }
#pragma unroll 2
        for (int jq = 0; jq < NQ; ++jq) {
            int j = 4 * jq;
            float4 t0 = s_t[j], t1 = s_t[j+1], t2 = s_t[j+2], t3 = s_t[j+3];
#pragma unroll
            for (int i = 0; i < PPT; ++i) {
                float d0 = fmaf(nax[i], t0.x, fmaf(nay[i], t0.y, fmaf(naz[i], t0.z, t0.w)));
                float d1 = fmaf(nax[i], t1.x, fmaf(nay[i], t1.y, fmaf(naz[i], t1.z, t1.w)));
                float d2 = fmaf(nax[i], t2.x, fmaf(nay[i], t2.y, fmaf(naz[i], t2.z, t2.w)));
                float d3 = fmaf(nax[i], t3.x, fmaf(nay[i], t3.y, fmaf(naz[i], t3.z, t3.w)));
                float u = min3f(d0, d1, d2);
                mgt[i] = min3f(u, d3, mgt[i]);
            }
        }
        float lN_gt = 0.0f;
        unsigned int gcbits = 0;
#pragma unroll
        for (int i = 0; i < PPT; ++i) {
            float a2 = px[i]*px[i] + py[i]*py[i] + pz[i]*pz[i];
            float dgt = fmaxf(a2 + mgt[i], 0.0f);
            if (sqrtf(dgt) < 0.005f) { lN_gt += 1.0f; gcbits |= (1u << i); }
        }
        gcA[(size_t)r * 256 + tid] = (unsigned char)gcbits;
        atomicAdd(&s_red[0], lN_gt);
        __syncthreads();
        if (tid == 0) atomicAdd(&acc[5], s_red[0]);
    } else {
        // ============ CHAMFER ROLE (4 sources/thread) ============
        int c   = blk - (REC_BLOCKS + GT_BLOCKS);
        int b   = c >> 1;
        int dir = c & 1;           // 0: rec->gt, 1: gt->rec
        const float4* base = ws4 + (size_t)b * BATCH_F4;
        const float4* srcv = dir ? base : (base + NVP);   // gt4 : rec4p
        const float4* tgtv = dir ? (base + NVP) : base;   // rec4p : gt4
        for (int j = tid; j < NVP; j += 256) s_t[j] = tgtv[j];
        if (tid == 0) s_red[0] = 0.0f;
        __syncthreads();

        const int CPT = 4;
        float nax[CPT], nay[CPT], naz[CPT], a2[CPT], m[CPT];
        bool valid[CPT];
#pragma unroll
        for (int k = 0; k < CPT; ++k) {
            int p = tid + 256 * k;
            valid[k] = (p < NV);
            float4 s = srcv[valid[k] ? p : 0];
            nax[k] = -2.0f * s.x; nay[k] = -2.0f * s.y; naz[k] = -2.0f * s.z;
            a2[k] = s.w;                  // one of src/tgt carries +BIAS
            m[k] = 3.4e38f;
        }
#pragma unroll 2
        for (int j = 0; j < NVP; j += 4) {
            float4 t0 = s_t[j], t1 = s_t[j+1], t2 = s_t[j+2], t3 = s_t[j+3];
#pragma unroll
            for (int k = 0; k < CPT; ++k) {
                float d0 = fmaf(nax[k], t0.x, fmaf(nay[k], t0.y, fmaf(naz[k], t0.z, t0.w)));
                float d1 = fmaf(nax[k], t1.x, fmaf(nay[k], t1.y, fmaf(naz[k], t1.z, t1.w)));
                float d2 = fmaf(nax[k], t2.x, fmaf(nay[k], t2.y, fmaf(naz[k], t2.z, t2.w)));
                float d3 = fmaf(nax[k], t3.x, fmaf(nay[k], t3.y, fmaf(naz[k], t3.z, t3.w)));
                float u = min3f(d0, d1, d2);
                m[k] = min3f(u, d3, m[k]);
            }
        }
        float local = 0.0f;
#pragma unroll
        for (int k = 0; k < CPT; ++k)
            if (valid[k]) local += fmaxf(a2[k] + m[k] - BIAS, 0.0f);
        atomicAdd(&s_red[0], local);
        __syncthreads();
        if (tid == 0) atomicAdd(&acc[2], s_red[0]);
    }

    // ================= TICKET + FINALIZE (last block of the 640) =================
    __syncthreads();   // all this block's global stores/atomics retired (to this XCD's L2)
    if (tid == 0) {
        __threadfence();                 // release: publish this XCD's L2
        s_tk = atomicAdd((unsigned int*)&acc[15], 1u);
    }
    __syncthreads();
    if (s_tk == NROLE_BLOCKS - 1) {
        __threadfence();                 // acquire: invalidate caches before cross-XCD reads
        if (tid < 4) s_red[4 + tid] = 0.0f;
        __syncthreads();
        // consistency popcount over rc & gc words
        const unsigned int* rcW = (const unsigned int*)rcA;
        const unsigned int* gcW = (const unsigned int*)gcA;
        float lcons = 0.0f;
        for (int i = tid; i < NPTS / 32; i += 256)
            lcons += (float)__popc(rcW[i] & gcW[i]);
        float s_param = 0.0f, s_kld = 0.0f;
        for (int i = tid; i < NB * NPAR; i += 256) {
            float d = rp[i] - xp[i];
            s_param += d * d;
        }
        for (int i = tid; i < NB * NZ; i += 256) {
            float mv = mean[i], lv = log_var[i];
            s_kld += 1.0f + lv - mv * mv - expf(lv);
        }
        atomicAdd(&s_red[4], lcons);
        atomicAdd(&s_red[5], s_param);
        atomicAdd(&s_red[6], s_kld);
        __syncthreads();
        if (tid == 0) {
            const float fB = 64.0f;
            float a2v = __hip_atomic_load(&acc[2], __ATOMIC_RELAXED, __HIP_MEMORY_SCOPE_AGENT);
            float a3  = __hip_atomic_load(&acc[3], __ATOMIC_RELAXED, __HIP_MEMORY_SCOPE_AGENT);
            float a4  = __hip_atomic_load(&acc[4], __ATOMIC_RELAXED, __HIP_MEMORY_SCOPE_AGENT);
            float a5  = __hip_atomic_load(&acc[5], __ATOMIC_RELAXED, __HIP_MEMORY_SCOPE_AGENT);
            float a7  = __hip_atomic_load(&acc[7], __ATOMIC_RELAXED, __HIP_MEMORY_SCOPE_AGENT);
            float param_loss  = s_red[5] / fB;
            float KLD         = -0.5f * s_red[6] / fB * 10.0f;
            float recon_loss  = a2v / fB;
            float cmap_loss   = 3000.0f * a3 / (fB * a4);
            float consistency = -5.0f * s_red[4] / (a5 + 0.0001f);
            float penetr      = 100.0f * a7 / fB;
            out[0] = (recon_loss + KLD) + 0.1f * param_loss + 1000.0f * cmap_loss
                   + 10.0f * consistency + 10.0f * penetr;
        }
    }
}

extern "C" void kernel_launch(void* const* d_in, const int* in_sizes, int n_in,
                              void* d_out, int out_size, void* d_ws, size_t ws_size,
                              hipStream_t stream) {
    (void)in_sizes; (void)n_in; (void)out_size; (void)ws_size;
    const float* obj     = (const float*)d_in[0];
    const float* recon   = (const float*)d_in[1];
    const float* gt      = (const float*)d_in[2];
    const float* mean    = (const float*)d_in[3];
    const float* log_var = (const float*)d_in[4];
    const float* rp      = (const float*)d_in[5];
    const float* xp      = (const float*)d_in[6];
    const int*   faces   = (const int*)d_in[7];
    float* acc  = (float*)d_ws + ACC_OFF;
    float4* ws4 = (float4*)d_ws;
    unsigned char* rcA = (unsigned char*)((float*)d_ws + RC_OFF);
    unsigned char* gcA = (unsigned char*)((float*)d_ws + GC_OFF);
    float* out  = (float*)d_out;

    k_prep <<<PREP_BLOCKS,  256, 0, stream>>>(recon, gt, faces, ws4, acc);
    k_fused<<<NROLE_BLOCKS, 256, 0, stream>>>(obj, ws4, acc, rcA, gcA,
                                              mean, log_var, rp, xp, out);
}

// Round 7
// 198.362 us; speedup vs baseline: 1.1407x; 1.0420x over previous
//
#include <hip/hip_runtime.h>
#include <math.h>

// Problem constants (from reference setup_inputs)
#define NB     64      // batch
#define N1V    8192    // obj points per batch
#define NPTS   (NB * N1V)
#define NV     778     // recon / gt verts
#define NVP    780     // padded to multiple of 4
#define NQ     195     // target quads
#define SEG1Q  51      // first 51 quads = 204 permuted targets = PRIOR set
#define NFACE  1538
#define NZ     64
#define NPAR   61
#define NPRIOR 204
#define PPT    8       // obj points per thread (rec/gt roles)
#define BIAS   0.0625f // 2|a||t| <= 0.06 < BIAS -> biased rec partials stay >= 0

// k_fused roles (R0 geometry: 256-thr blocks, 640 total)
#define REC_BLOCKS 256                 // (batch, chunk-of-2048)
#define GT_BLOCKS  256
#define CH_BLOCKS  128                 // (batch, dir)
#define NROLE_BLOCKS (REC_BLOCKS + GT_BLOCKS + CH_BLOCKS)   // 640

// k_prep: 3 roles x 64 batches + 1 param/KLD block = 193 blocks
#define PREP_BLOCKS 193

// ws float4 layout per batch (BATCH_F4 float4s):
//   [0,780)     gt4    (x,y,z,|t|^2)  original order, pads w=1e30
//   [780,1560)  rec4p  (x,y,z,|t|^2+BIAS) PERMUTED (prior first), pads w=1e30
//   [1560,2340) nrm4p  (nx,ny,nz,0)   RAW face-normal sums, PERMUTED (sign-only use)
#define BATCH_F4 2352                  // padded stride
// float offsets in ws
#define ACC_OFF (NB * BATCH_F4 * 4)   // acc[16]
#define RC_OFF  (ACC_OFF + 16)        // uchar[NPTS/8] rec-cmap bits (1/pt)
#define GC_OFF  (RC_OFF + NPTS / 32)  // uchar[NPTS/8] gt-cmap bits
// acc slots: 2 chamfer, 3 S_cmap, 4 N_cmap, 5 N_gt, 7 S_pen, 8 param, 9 kld, 15 ticket

// ---- compile-time prior permutation (pure function of the static index list) ----
static constexpr int PRIOR_LIST[NPRIOR] = {
  697,698,699,700,712,713,714,715,737,738,739,740,741,743,744,745,746,748,749,750,
  753,754,755,756,757,758,759,760,761,762,763,764,765,766,767,768,
  46,47,48,49,164,165,166,167,194,195,223,237,238,280,281,298,301,317,320,323,
  324,325,326,327,328,329,330,331,332,333,340,341,342,343,344,345,346,347,348,349,
  350,351,352,353,354,355,
  356,357,358,359,375,376,386,387,396,397,402,403,413,429,433,434,435,436,437,438,
  439,440,441,442,443,444,452,453,454,455,456,459,460,461,462,463,464,465,466,467,
  468,469,470,471,484,485,486,496,497,506,507,513,514,524,545,546,547,548,549,550,
  551,552,553,555,563,564,565,566,567,570,572,573,574,575,576,577,578,
  580,581,582,583,600,601,602,614,615,624,625,630,631,641,663,664,665,666,667,668,
  670,672,680,681,682,683,684,686,687,688,689,690,691,692,693,694,695,
  73,96,98,99,772,774,775,777
};

struct PermT { unsigned short v[NV]; };
static constexpr PermT make_perm() {
    PermT t{};
    bool mem[NV] = {};
    for (int i = 0; i < NPRIOR; ++i) mem[PRIOR_LIST[i]] = true;
    int a = 0, b = NPRIOR;
    for (int j = 0; j < NV; ++j) {
        if (mem[j]) t.v[a++] = (unsigned short)j;
        else        t.v[b++] = (unsigned short)j;
    }
    return t;
}
__device__ __constant__ PermT c_perm = make_perm();

// ---------------- Kernel 0: prep, parallel roles ------
// role 0 (blk 0..63):    gt4 stream (+acc[0..7],[15] init on b==0)
// role 1 (blk 64..127):  rec4p permuted stream
// role 2 (blk 128..191): face normals (RAW sums) -> nrm4p permuted
// blk 192:               param + KLD sums -> acc[8], acc[9] (plain stores)
__global__ __launch_bounds__(256) void k_prep(const float* __restrict__ recon,
                                              const float* __restrict__ gt,
                                              const int* __restrict__ faces,
                                              const float* __restrict__ mean,
                                              const float* __restrict__ log_var,
                                              const float* __restrict__ rp,
                                              const float* __restrict__ xp,
                                              float4* __restrict__ ws4,
                                              float* __restrict__ acc) {
    int blk = blockIdx.x, tid = threadIdx.x;

    if (blk == 192) {
        // ---- param + KLD (one block; plain stores, no init dependence) ----
        __shared__ float sp[2];
        if (tid < 2) sp[tid] = 0.0f;
        __syncthreads();
        float s_param = 0.0f, s_kld = 0.0f;
        for (int i = tid; i < NB * NPAR; i += 256) {
            float d = rp[i] - xp[i];
            s_param += d * d;
        }
        for (int i = tid; i < NB * NZ; i += 256) {
            float mv = mean[i], lv = log_var[i];
            s_kld += 1.0f + lv - mv * mv - expf(lv);
        }
        atomicAdd(&sp[0], s_param);
        atomicAdd(&sp[1], s_kld);
        __syncthreads();
        if (tid == 0) { acc[8] = sp[0]; acc[9] = sp[1]; }
        return;
    }

    int b = blk & 63, role = blk >> 6;
    float4* gt4   = ws4 + (size_t)b * BATCH_F4;
    float4* rec4p = gt4 + NVP;
    float4* nrm4p = rec4p + NVP;

    if (role == 0) {
        // ---- GT stream ----
        if (b == 0 && tid < 8) acc[tid] = 0.0f;
        if (b == 0 && tid == 15) acc[15] = 0.0f;
        const float* gb = gt + (size_t)b * NV * 3;
        for (int j = tid; j < NV; j += 256) {
            float x = gb[3*j], y = gb[3*j+1], z = gb[3*j+2];
            gt4[j] = make_float4(x, y, z, x*x + y*y + z*z);
        }
        if (tid < 2) gt4[NV + tid] = make_float4(0.f, 0.f, 0.f, 1e30f);
        return;
    }

    if (role == 1) {
        // ---- REC permuted stream (gather via constexpr perm) ----
        const float* rb = recon + (size_t)b * NV * 3;
        for (int j = tid; j < NVP; j += 256) {
            if (j < NV) {
                int src = c_perm.v[j];
                float x = rb[3*src], y = rb[3*src+1], z = rb[3*src+2];
                rec4p[j] = make_float4(x, y, z, x*x + y*y + z*z + BIAS);
            } else {
                rec4p[j] = make_float4(0.f, 0.f, 0.f, 1e30f);
            }
        }
        return;
    }

    // ---- role 2: face normals (raw sums; only the SIGN of dot(nn_v-p, n) is used) ----
    {
        __shared__ float s_x[NV], s_y[NV], s_z[NV];
        __shared__ float s_vnx[NV], s_vny[NV], s_vnz[NV];
        const float* rb = recon + (size_t)b * NV * 3;
        for (int j = tid; j < NV; j += 256) {
            s_x[j] = rb[3*j]; s_y[j] = rb[3*j+1]; s_z[j] = rb[3*j+2];
            s_vnx[j] = 0.0f; s_vny[j] = 0.0f; s_vnz[j] = 0.0f;
        }
        __syncthreads();
        for (int f = tid; f < NFACE; f += 256) {
            int i0 = faces[3*f], i1 = faces[3*f+1], i2 = faces[3*f+2];
            float p0x = s_x[i0], p0y = s_y[i0], p0z = s_z[i0];
            float e1x = s_x[i1] - p0x, e1y = s_y[i1] - p0y, e1z = s_z[i1] - p0z;
            float e2x = s_x[i2] - p0x, e2y = s_y[i2] - p0y, e2z = s_z[i2] - p0z;
            float fx = e1y * e2z - e1z * e2y;
            float fy = e1z * e2x - e1x * e2z;
            float fz = e1x * e2y - e1y * e2x;
            atomicAdd(&s_vnx[i0], fx); atomicAdd(&s_vny[i0], fy); atomicAdd(&s_vnz[i0], fz);
            atomicAdd(&s_vnx[i1], fx); atomicAdd(&s_vny[i1], fy); atomicAdd(&s_vnz[i1], fz);
            atomicAdd(&s_vnx[i2], fx); atomicAdd(&s_vny[i2], fy); atomicAdd(&s_vnz[i2], fz);
        }
        __syncthreads();
        for (int j = tid; j < NVP; j += 256) {
            if (j < NV) {
                int src = c_perm.v[j];
                nrm4p[j] = make_float4(s_vnx[src], s_vny[src], s_vnz[src], 0.0f);
            } else {
                nrm4p[j] = make_float4(0.f, 0.f, 1.f, 0.0f);
            }
        }
    }
}

#define LOAD_PTS(ob)                                                          \
    const float4* ob4 = (const float4*)((ob) + (size_t)tid * 24);             \
    float4 q0 = ob4[0], q1 = ob4[1], q2 = ob4[2],                             \
           q3 = ob4[3], q4 = ob4[4], q5 = ob4[5];                             \
    float px[PPT], py[PPT], pz[PPT];                                          \
    px[0]=q0.x; py[0]=q0.y; pz[0]=q0.z;  px[1]=q0.w; py[1]=q1.x; pz[1]=q1.y;  \
    px[2]=q1.z; py[2]=q1.w; pz[2]=q2.x;  px[3]=q2.y; py[3]=q2.z; pz[3]=q2.w;  \
    px[4]=q3.x; py[4]=q3.y; pz[4]=q3.z;  px[5]=q3.w; py[5]=q4.x; pz[5]=q4.y;  \
    px[6]=q4.z; py[6]=q4.w; pz[6]=q5.x;  px[7]=q5.y; py[7]=q5.z; pz[7]=q5.w;

// ---------------- Fused role kernel (EXACT R0 core) + ticket finalize tail ----
// [0,256): rec quad-argmin + epilogue  [256,512): gt min + gc bits
// [512,640): chamfer.  Last block to finish: popcount + final loss.
__global__ __launch_bounds__(256) void k_fused(const float* __restrict__ obj,
                                               const float4* __restrict__ ws4,
                                               float* __restrict__ acc,
                                               unsigned char* __restrict__ rcA,
                                               unsigned char* __restrict__ gcA,
                                               float* __restrict__ out) {
    __shared__ float4 s_t[NVP];
    __shared__ float s_red[4];
    __shared__ unsigned int s_tk;
    int tid = threadIdx.x;
    int blk = blockIdx.x;

    if (blk < REC_BLOCKS) {
        // ============ REC ROLE: scan + inline epilogue (R0 verbatim) ============
        int b = blk >> 2, chunk = blk & 3;
        const float4* base = ws4 + (size_t)b * BATCH_F4;
        const float4* rec4p = base + NVP;
        const float4* nrm4p = base + 2 * NVP;
        for (int j = tid; j < NVP; j += 256) s_t[j] = rec4p[j];
        if (tid < 3) s_red[tid] = 0.0f;
        __syncthreads();

        const float* ob = obj + ((size_t)b * N1V + (size_t)chunk * 2048) * 3;
        LOAD_PTS(ob)
        float nax[PPT], nay[PPT], naz[PPT], m[PPT];
        int q[PPT];
#pragma unroll
        for (int i = 0; i < PPT; ++i) {
            nax[i] = -2.0f * px[i]; nay[i] = -2.0f * py[i]; naz[i] = -2.0f * pz[i];
            m[i] = 3.4e38f; q[i] = 0;
        }
        float mp[PPT];
#pragma unroll 1
        for (int jq = 0; jq < SEG1Q; ++jq) {
            int j = 4 * jq;
            float4 t0 = s_t[j], t1 = s_t[j+1], t2 = s_t[j+2], t3 = s_t[j+3];
#pragma unroll
            for (int i = 0; i < PPT; ++i) {
                float d0 = fmaf(nax[i], t0.x, fmaf(nay[i], t0.y, fmaf(naz[i], t0.z, t0.w)));
                float d1 = fmaf(nax[i], t1.x, fmaf(nay[i], t1.y, fmaf(naz[i], t1.z, t1.w)));
                float d2 = fmaf(nax[i], t2.x, fmaf(nay[i], t2.y, fmaf(naz[i], t2.z, t2.w)));
                float d3 = fmaf(nax[i], t3.x, fmaf(nay[i], t3.y, fmaf(naz[i], t3.z, t3.w)));
                float mn = fminf(fminf(fminf(d0, d1), fminf(d2, d3)), m[i]);
                q[i] = (mn < m[i]) ? jq : q[i];
                m[i] = mn;
            }
        }
#pragma unroll
        for (int i = 0; i < PPT; ++i) mp[i] = m[i];   // prior min snapshot
#pragma unroll 1
        for (int jq = SEG1Q; jq < NQ; ++jq) {
            int j = 4 * jq;
            float4 t0 = s_t[j], t1 = s_t[j+1], t2 = s_t[j+2], t3 = s_t[j+3];
#pragma unroll
            for (int i = 0; i < PPT; ++i) {
                float d0 = fmaf(nax[i], t0.x, fmaf(nay[i], t0.y, fmaf(naz[i], t0.z, t0.w)));
                float d1 = fmaf(nax[i], t1.x, fmaf(nay[i], t1.y, fmaf(naz[i], t1.z, t1.w)));
                float d2 = fmaf(nax[i], t2.x, fmaf(nay[i], t2.y, fmaf(naz[i], t2.z, t2.w)));
                float d3 = fmaf(nax[i], t3.x, fmaf(nay[i], t3.y, fmaf(naz[i], t3.z, t3.w)));
                float mn = fminf(fminf(fminf(d0, d1), fminf(d2, d3)), m[i]);
                q[i] = (mn < m[i]) ? jq : q[i];
                m[i] = mn;
            }
        }
        // ---- inline epilogue ----
        float lS_cmap = 0.0f, lN_cmap = 0.0f, lS_pen = 0.0f;
        unsigned int rcbits = 0;
#pragma unroll
        for (int i = 0; i < PPT; ++i) {
            float a2 = px[i]*px[i] + py[i]*py[i] + pz[i]*pz[i];
            float drec = fmaxf(a2 + (m[i]  - BIAS), 0.0f);
            float dpri = fmaxf(a2 + (mp[i] - BIAS), 0.0f);
            bool cm = drec < 1e-4f;
            bool rc = sqrtf(drec) < 0.005f;
            if (cm) { lS_cmap += dpri; lN_cmap += 1.0f; }
            if (rc) rcbits |= (1u << i);
            // winning-quad re-eval from LDS for jstar (bit-identical fma chain)
            int jr = 4 * q[i];
            float4 t0 = s_t[jr], t1 = s_t[jr+1], t2 = s_t[jr+2], t3 = s_t[jr+3];
            float d0 = fmaf(nax[i], t0.x, fmaf(nay[i], t0.y, fmaf(naz[i], t0.z, t0.w)));
            float d1 = fmaf(nax[i], t1.x, fmaf(nay[i], t1.y, fmaf(naz[i], t1.z, t1.w)));
            float d2 = fmaf(nax[i], t2.x, fmaf(nay[i], t2.y, fmaf(naz[i], t2.z, t2.w)));
            float d3 = fmaf(nax[i], t3.x, fmaf(nay[i], t3.y, fmaf(naz[i], t3.z, t3.w)));
            float mmin = fminf(fminf(d0, d1), fminf(d2, d3));
            int off = (d0 == mmin) ? 0 : ((d1 == mmin) ? 1 : ((d2 == mmin) ? 2 : 3));
            int jstar = jr + off;
            float4 tS = s_t[jstar];
            float4 nr = nrm4p[jstar];   // RAW normal sum: only sign of ddot matters
            float ddot = (tS.x - px[i]) * nr.x + (tS.y - py[i]) * nr.y
                       + (tS.z - pz[i]) * nr.z;
            if (ddot > 0.0f) lS_pen += drec;
        }
        rcA[(size_t)blk * 256 + tid] = (unsigned char)rcbits;
        atomicAdd(&s_red[0], lS_cmap);
        atomicAdd(&s_red[1], lN_cmap);
        atomicAdd(&s_red[2], lS_pen);
        __syncthreads();
        if (tid == 0) atomicAdd(&acc[3], s_red[0]);
        if (tid == 1) atomicAdd(&acc[4], s_red[1]);
        if (tid == 2) atomicAdd(&acc[7], s_red[2]);
    } else if (blk < REC_BLOCKS + GT_BLOCKS) {
        // ============ GT ROLE: min scan + gc bits (R0 verbatim) ============
        int r = blk - REC_BLOCKS;
        int b = r >> 2, chunk = r & 3;
        const float4* gt4v = ws4 + (size_t)b * BATCH_F4;
        for (int j = tid; j < NVP; j += 256) s_t[j] = gt4v[j];
        if (tid == 0) s_red[0] = 0.0f;
        __syncthreads();

        const float* ob = obj + ((size_t)b * N1V + (size_t)chunk * 2048) * 3;
        LOAD_PTS(ob)
        float nax[PPT], nay[PPT], naz[PPT], mgt[PPT];
#pragma unroll
        for (int i = 0; i < PPT; ++i) {
            nax[i] = -2.0f * px[i]; nay[i] = -2.0f * py[i]; naz[i] = -2.0f * pz[i];
            mgt[i] = 3.4e38f;
        }
#pragma unroll 1
        for (int jq = 0; jq < NQ; ++jq) {
            int j = 4 * jq;
            float4 t0 = s_t[j], t1 = s_t[j+1], t2 = s_t[j+2], t3 = s_t[j+3];
#pragma unroll
            for (int i = 0; i < PPT; ++i) {
                float d0 = fmaf(nax[i], t0.x, fmaf(nay[i], t0.y, fmaf(naz[i], t0.z, t0.w)));
                float d1 = fmaf(nax[i], t1.x, fmaf(nay[i], t1.y, fmaf(naz[i], t1.z, t1.w)));
                float d2 = fmaf(nax[i], t2.x, fmaf(nay[i], t2.y, fmaf(naz[i], t2.z, t2.w)));
                float d3 = fmaf(nax[i], t3.x, fmaf(nay[i], t3.y, fmaf(naz[i], t3.z, t3.w)));
                mgt[i] = fminf(fminf(mgt[i], fminf(d0, d1)), fminf(d2, d3));
            }
        }
        float lN_gt = 0.0f;
        unsigned int gcbits = 0;
#pragma unroll
        for (int i = 0; i < PPT; ++i) {
            float a2 = px[i]*px[i] + py[i]*py[i] + pz[i]*pz[i];
            float dgt = fmaxf(a2 + mgt[i], 0.0f);
            if (sqrtf(dgt) < 0.005f) { lN_gt += 1.0f; gcbits |= (1u << i); }
        }
        gcA[(size_t)r * 256 + tid] = (unsigned char)gcbits;
        atomicAdd(&s_red[0], lN_gt);
        __syncthreads();
        if (tid == 0) atomicAdd(&acc[5], s_red[0]);
    } else {
        // ============ CHAMFER ROLE (R0 verbatim) ============
        int c   = blk - (REC_BLOCKS + GT_BLOCKS);
        int b   = c >> 1;
        int dir = c & 1;           // 0: rec->gt, 1: gt->rec
        const float4* base = ws4 + (size_t)b * BATCH_F4;
        const float4* srcv = dir ? base : (base + NVP);   // gt4 : rec4p
        const float4* tgtv = dir ? (base + NVP) : base;   // rec4p : gt4
        for (int j = tid; j < NVP; j += 256) s_t[j] = tgtv[j];
        if (tid == 0) s_red[0] = 0.0f;
        __syncthreads();

        const int CPT = 4;
        float nax[CPT], nay[CPT], naz[CPT], a2[CPT], m[CPT];
        bool valid[CPT];
#pragma unroll
        for (int k = 0; k < CPT; ++k) {
            int p = tid + 256 * k;
            valid[k] = (p < NV);
            float4 s = srcv[valid[k] ? p : 0];
            nax[k] = -2.0f * s.x; nay[k] = -2.0f * s.y; naz[k] = -2.0f * s.z;
            a2[k] = s.w;                  // one of src/tgt carries +BIAS
            m[k] = 3.4e38f;
        }
#pragma unroll 1
        for (int j = 0; j < NVP; j += 4) {
            float4 t0 = s_t[j], t1 = s_t[j+1], t2 = s_t[j+2], t3 = s_t[j+3];
#pragma unroll
            for (int k = 0; k < CPT; ++k) {
                float d0 = fmaf(nax[k], t0.x, fmaf(nay[k], t0.y, fmaf(naz[k], t0.z, t0.w)));
                float d1 = fmaf(nax[k], t1.x, fmaf(nay[k], t1.y, fmaf(naz[k], t1.z, t1.w)));
                float d2 = fmaf(nax[k], t2.x, fmaf(nay[k], t2.y, fmaf(naz[k], t2.z, t2.w)));
                float d3 = fmaf(nax[k], t3.x, fmaf(nay[k], t3.y, fmaf(naz[k], t3.z, t3.w)));
                m[k] = fminf(fminf(m[k], fminf(d0, d1)), fminf(d2, d3));
            }
        }
        float local = 0.0f;
#pragma unroll
        for (int k = 0; k < CPT; ++k)
            if (valid[k]) local += fmaxf(a2[k] + m[k] - BIAS, 0.0f);
        atomicAdd(&s_red[0], local);
        __syncthreads();
        if (tid == 0) atomicAdd(&acc[2], s_red[0]);
    }

    // ================= TICKET + FINALIZE (last block; popcount + formula only) ==========
    __syncthreads();   // all this block's global stores/atomics retired
    if (tid == 0) {
        __threadfence();                 // release
        s_tk = atomicAdd((unsigned int*)&acc[15], 1u);
    }
    __syncthreads();
    if (s_tk == NROLE_BLOCKS - 1) {
        __threadfence();                 // acquire
        if (tid == 0) s_red[3] = 0.0f;
        __syncthreads();
        const unsigned int* rcW = (const unsigned int*)rcA;
        const unsigned int* gcW = (const unsigned int*)gcA;
        float lcons = 0.0f;
        for (int i = tid; i < NPTS / 32; i += 256)
            lcons += (float)__popc(rcW[i] & gcW[i]);
        atomicAdd(&s_red[3], lcons);
        __syncthreads();
        if (tid == 0) {
            const float fB = 64.0f;
            float a2v = __hip_atomic_load(&acc[2], __ATOMIC_RELAXED, __HIP_MEMORY_SCOPE_AGENT);
            float a3  = __hip_atomic_load(&acc[3], __ATOMIC_RELAXED, __HIP_MEMORY_SCOPE_AGENT);
            float a4  = __hip_atomic_load(&acc[4], __ATOMIC_RELAXED, __HIP_MEMORY_SCOPE_AGENT);
            float a5  = __hip_atomic_load(&acc[5], __ATOMIC_RELAXED, __HIP_MEMORY_SCOPE_AGENT);
            float a7  = __hip_atomic_load(&acc[7], __ATOMIC_RELAXED, __HIP_MEMORY_SCOPE_AGENT);
            float a8  = __hip_atomic_load(&acc[8], __ATOMIC_RELAXED, __HIP_MEMORY_SCOPE_AGENT);
            float a9  = __hip_atomic_load(&acc[9], __ATOMIC_RELAXED, __HIP_MEMORY_SCOPE_AGENT);
            float param_loss  = a8 / fB;
            float KLD         = -0.5f * a9 / fB * 10.0f;
            float recon_loss  = a2v / fB;
            float cmap_loss   = 3000.0f * a3 / (fB * a4);
            float consistency = -5.0f * s_red[3] / (a5 + 0.0001f);
            float penetr      = 100.0f * a7 / fB;
            out[0] = (recon_loss + KLD) + 0.1f * param_loss + 1000.0f * cmap_loss
                   + 10.0f * consistency + 10.0f * penetr;
        }
    }
}

extern "C" void kernel_launch(void* const* d_in, const int* in_sizes, int n_in,
                              void* d_out, int out_size, void* d_ws, size_t ws_size,
                              hipStream_t stream) {
    (void)in_sizes; (void)n_in; (void)out_size; (void)ws_size;
    const float* obj     = (const float*)d_in[0];
    const float* recon   = (const float*)d_in[1];
    const float* gt      = (const float*)d_in[2];
    const float* mean    = (const float*)d_in[3];
    const float* log_var = (const float*)d_in[4];
    const float* rp      = (const float*)d_in[5];
    const float* xp      = (const float*)d_in[6];
    const int*   faces   = (const int*)d_in[7];
    float* acc  = (float*)d_ws + ACC_OFF;
    float4* ws4 = (float4*)d_ws;
    unsigned char* rcA = (unsigned char*)((float*)d_ws + RC_OFF);
    unsigned char* gcA = (unsigned char*)((float*)d_ws + GC_OFF);
    float* out  = (float*)d_out;

    k_prep <<<PREP_BLOCKS,  256, 0, stream>>>(recon, gt, faces, mean, log_var,
                                              rp, xp, ws4, acc);
    k_fused<<<NROLE_BLOCKS, 256, 0, stream>>>(obj, ws4, acc, rcA, gcA, out);
}

// Round 8
// 189.689 us; speedup vs baseline: 1.1929x; 1.0457x over previous
//
#include <hip/hip_runtime.h>
#include <math.h>

// Problem constants (from reference setup_inputs)
#define NB     64      // batch
#define N1V    8192    // obj points per batch
#define NPTS   (NB * N1V)
#define NV     778     // recon / gt verts
#define NVP    780     // padded to multiple of 4
#define NQ     195     // target quads
#define SEG1Q  51      // first 51 quads = 204 permuted targets = PRIOR set
#define NFACE  1538
#define NZ     64
#define NPAR   61
#define NPRIOR 204
#define PPT    8       // obj points per thread (rec/gt roles)
#define BIAS   0.0625f // 2|a||t| <= 0.06 < BIAS -> biased rec partials stay >= 0

// k_fused roles (R0 geometry, REORDERED: gt first so rec can consume gc bytes)
#define GT_BLOCKS  256                 // blocks [0,256): (batch, chunk-of-2048)
#define REC_BLOCKS 256                 // blocks [256,512)
#define CH_BLOCKS  128                 // blocks [512,640): (batch, dir)
#define NROLE_BLOCKS (GT_BLOCKS + REC_BLOCKS + CH_BLOCKS)   // 640

// k_prep: 3 roles x 64 batches + 1 aux block = 193 blocks
#define PREP_BLOCKS 193

// ws float4 layout per batch (BATCH_F4 float4s):
//   [0,780)     gt4    (x,y,z,|t|^2)  original order, pads w=1e30
//   [780,1560)  rec4p  (x,y,z,|t|^2+BIAS) PERMUTED (prior first), pads w=1e30
//   [1560,2340) nrm4p  (nx,ny,nz,0)   RAW face-normal sums, PERMUTED (sign-only use)
#define BATCH_F4 2352                  // padded stride
// float offsets in ws
#define ACC_OFF   (NB * BATCH_F4 * 4)   // acc[16]
#define FLAGS_OFF (ACC_OFF + 16)        // uint flags[256]: per gt-chunk release
#define GC_OFF    (FLAGS_OFF + 256)     // uchar[NPTS/8] gt-cmap bits
// acc slots: 2 chamfer, 3 S_cmap, 4 N_cmap, 5 N_gt, 6 N_cons, 7 S_pen,
//            8 param, 9 kld, 15 ticket

// ---- compile-time prior permutation (pure function of the static index list) ----
static constexpr int PRIOR_LIST[NPRIOR] = {
  697,698,699,700,712,713,714,715,737,738,739,740,741,743,744,745,746,748,749,750,
  753,754,755,756,757,758,759,760,761,762,763,764,765,766,767,768,
  46,47,48,49,164,165,166,167,194,195,223,237,238,280,281,298,301,317,320,323,
  324,325,326,327,328,329,330,331,332,333,340,341,342,343,344,345,346,347,348,349,
  350,351,352,353,354,355,
  356,357,358,359,375,376,386,387,396,397,402,403,413,429,433,434,435,436,437,438,
  439,440,441,442,443,444,452,453,454,455,456,459,460,461,462,463,464,465,466,467,
  468,469,470,471,484,485,486,496,497,506,507,513,514,524,545,546,547,548,549,550,
  551,552,553,555,563,564,565,566,567,570,572,573,574,575,576,577,578,
  580,581,582,583,600,601,602,614,615,624,625,630,631,641,663,664,665,666,667,668,
  670,672,680,681,682,683,684,686,687,688,689,690,691,692,693,694,695,
  73,96,98,99,772,774,775,777
};

struct PermT { unsigned short v[NV]; };
static constexpr PermT make_perm() {
    PermT t{};
    bool mem[NV] = {};
    for (int i = 0; i < NPRIOR; ++i) mem[PRIOR_LIST[i]] = true;
    int a = 0, b = NPRIOR;
    for (int j = 0; j < NV; ++j) {
        if (mem[j]) t.v[a++] = (unsigned short)j;
        else        t.v[b++] = (unsigned short)j;
    }
    return t;
}
__device__ __constant__ PermT c_perm = make_perm();

// ---------------- Kernel 0: prep, parallel roles ------
// role 0 (blk 0..63):    gt4 stream (+acc init on b==0)
// role 1 (blk 64..127):  rec4p permuted stream
// role 2 (blk 128..191): face normals (RAW sums) -> nrm4p permuted
// blk 192:               param/KLD sums -> acc[8..9]; zero flags[256]
__global__ __launch_bounds__(256) void k_prep(const float* __restrict__ recon,
                                              const float* __restrict__ gt,
                                              const int* __restrict__ faces,
                                              const float* __restrict__ mean,
                                              const float* __restrict__ log_var,
                                              const float* __restrict__ rp,
                                              const float* __restrict__ xp,
                                              float4* __restrict__ ws4,
                                              float* __restrict__ acc,
                                              unsigned int* __restrict__ flags) {
    int blk = blockIdx.x, tid = threadIdx.x;

    if (blk == 192) {
        // ---- flags zero + param + KLD (plain stores; completes before k_fused) ----
        flags[tid] = 0u;
        __shared__ float sp[2];
        if (tid < 2) sp[tid] = 0.0f;
        __syncthreads();
        float s_param = 0.0f, s_kld = 0.0f;
        for (int i = tid; i < NB * NPAR; i += 256) {
            float d = rp[i] - xp[i];
            s_param += d * d;
        }
        for (int i = tid; i < NB * NZ; i += 256) {
            float mv = mean[i], lv = log_var[i];
            s_kld += 1.0f + lv - mv * mv - expf(lv);
        }
        atomicAdd(&sp[0], s_param);
        atomicAdd(&sp[1], s_kld);
        __syncthreads();
        if (tid == 0) { acc[8] = sp[0]; acc[9] = sp[1]; }
        return;
    }

    int b = blk & 63, role = blk >> 6;
    float4* gt4   = ws4 + (size_t)b * BATCH_F4;
    float4* rec4p = gt4 + NVP;
    float4* nrm4p = rec4p + NVP;

    if (role == 0) {
        // ---- GT stream ----
        if (b == 0 && tid < 8) acc[tid] = 0.0f;
        if (b == 0 && tid == 15) acc[15] = 0.0f;
        const float* gb = gt + (size_t)b * NV * 3;
        for (int j = tid; j < NV; j += 256) {
            float x = gb[3*j], y = gb[3*j+1], z = gb[3*j+2];
            gt4[j] = make_float4(x, y, z, x*x + y*y + z*z);
        }
        if (tid < 2) gt4[NV + tid] = make_float4(0.f, 0.f, 0.f, 1e30f);
        return;
    }

    if (role == 1) {
        // ---- REC permuted stream (gather via constexpr perm) ----
        const float* rb = recon + (size_t)b * NV * 3;
        for (int j = tid; j < NVP; j += 256) {
            if (j < NV) {
                int src = c_perm.v[j];
                float x = rb[3*src], y = rb[3*src+1], z = rb[3*src+2];
                rec4p[j] = make_float4(x, y, z, x*x + y*y + z*z + BIAS);
            } else {
                rec4p[j] = make_float4(0.f, 0.f, 0.f, 1e30f);
            }
        }
        return;
    }

    // ---- role 2: face normals (raw sums; only the SIGN of dot(nn_v-p, n) is used) ----
    {
        __shared__ float s_x[NV], s_y[NV], s_z[NV];
        __shared__ float s_vnx[NV], s_vny[NV], s_vnz[NV];
        const float* rb = recon + (size_t)b * NV * 3;
        for (int j = tid; j < NV; j += 256) {
            s_x[j] = rb[3*j]; s_y[j] = rb[3*j+1]; s_z[j] = rb[3*j+2];
            s_vnx[j] = 0.0f; s_vny[j] = 0.0f; s_vnz[j] = 0.0f;
        }
        __syncthreads();
        for (int f = tid; f < NFACE; f += 256) {
            int i0 = faces[3*f], i1 = faces[3*f+1], i2 = faces[3*f+2];
            float p0x = s_x[i0], p0y = s_y[i0], p0z = s_z[i0];
            float e1x = s_x[i1] - p0x, e1y = s_y[i1] - p0y, e1z = s_z[i1] - p0z;
            float e2x = s_x[i2] - p0x, e2y = s_y[i2] - p0y, e2z = s_z[i2] - p0z;
            float fx = e1y * e2z - e1z * e2y;
            float fy = e1z * e2x - e1x * e2z;
            float fz = e1x * e2y - e1y * e2x;
            atomicAdd(&s_vnx[i0], fx); atomicAdd(&s_vny[i0], fy); atomicAdd(&s_vnz[i0], fz);
            atomicAdd(&s_vnx[i1], fx); atomicAdd(&s_vny[i1], fy); atomicAdd(&s_vnz[i1], fz);
            atomicAdd(&s_vnx[i2], fx); atomicAdd(&s_vny[i2], fy); atomicAdd(&s_vnz[i2], fz);
        }
        __syncthreads();
        for (int j = tid; j < NVP; j += 256) {
            if (j < NV) {
                int src = c_perm.v[j];
                nrm4p[j] = make_float4(s_vnx[src], s_vny[src], s_vnz[src], 0.0f);
            } else {
                nrm4p[j] = make_float4(0.f, 0.f, 1.f, 0.0f);
            }
        }
    }
}

#define LOAD_PTS(ob)                                                          \
    const float4* ob4 = (const float4*)((ob) + (size_t)tid * 24);             \
    float4 q0 = ob4[0], q1 = ob4[1], q2 = ob4[2],                             \
           q3 = ob4[3], q4 = ob4[4], q5 = ob4[5];                             \
    float px[PPT], py[PPT], pz[PPT];                                          \
    px[0]=q0.x; py[0]=q0.y; pz[0]=q0.z;  px[1]=q0.w; py[1]=q1.x; pz[1]=q1.y;  \
    px[2]=q1.z; py[2]=q1.w; pz[2]=q2.x;  px[3]=q2.y; py[3]=q2.z; pz[3]=q2.w;  \
    px[4]=q3.x; py[4]=q3.y; pz[4]=q3.z;  px[5]=q3.w; py[5]=q4.x; pz[5]=q4.y;  \
    px[6]=q4.z; py[6]=q4.w; pz[6]=q5.x;  px[7]=q5.y; py[7]=q5.z; pz[7]=q5.w;

__device__ __forceinline__ void spin_wait(unsigned int* f, int tid) {
    if (tid == 0) {
        while (__hip_atomic_load(f, __ATOMIC_ACQUIRE, __HIP_MEMORY_SCOPE_AGENT) == 0u)
            __builtin_amdgcn_s_sleep(2);
    }
    __syncthreads();   // tid0's acquire + barrier orders subsequent reads
}

// ---------------- Fused role kernel (R0 core) -------------------------------
// [0,256): gt min + gc bits + flag release   [256,512): rec scan + epilogue +
// local consistency (gc AND)   [512,640): chamfer.
// Last ticket block: formula only (~1 us).
__global__ __launch_bounds__(256) void k_fused(const float* __restrict__ obj,
                                               const float4* __restrict__ ws4,
                                               float* __restrict__ acc,
                                               unsigned int* __restrict__ flags,
                                               unsigned char* __restrict__ gcA,
                                               float* __restrict__ out) {
    __shared__ float4 s_t[NVP];
    __shared__ float s_red[4];
    __shared__ unsigned int s_tk;
    int tid = threadIdx.x;
    int blk = blockIdx.x;

    if (blk < GT_BLOCKS) {
        // ============ GT ROLE: min scan + gc bits + release (R0 core) ============
        int r = blk;
        int b = r >> 2, chunk = r & 3;
        const float4* gt4v = ws4 + (size_t)b * BATCH_F4;
        for (int j = tid; j < NVP; j += 256) s_t[j] = gt4v[j];
        if (tid == 0) s_red[0] = 0.0f;
        __syncthreads();

        const float* ob = obj + ((size_t)b * N1V + (size_t)chunk * 2048) * 3;
        LOAD_PTS(ob)
        float nax[PPT], nay[PPT], naz[PPT], mgt[PPT];
#pragma unroll
        for (int i = 0; i < PPT; ++i) {
            nax[i] = -2.0f * px[i]; nay[i] = -2.0f * py[i]; naz[i] = -2.0f * pz[i];
            mgt[i] = 3.4e38f;
        }
#pragma unroll 1
        for (int jq = 0; jq < NQ; ++jq) {
            int j = 4 * jq;
            float4 t0 = s_t[j], t1 = s_t[j+1], t2 = s_t[j+2], t3 = s_t[j+3];
#pragma unroll
            for (int i = 0; i < PPT; ++i) {
                float d0 = fmaf(nax[i], t0.x, fmaf(nay[i], t0.y, fmaf(naz[i], t0.z, t0.w)));
                float d1 = fmaf(nax[i], t1.x, fmaf(nay[i], t1.y, fmaf(naz[i], t1.z, t1.w)));
                float d2 = fmaf(nax[i], t2.x, fmaf(nay[i], t2.y, fmaf(naz[i], t2.z, t2.w)));
                float d3 = fmaf(nax[i], t3.x, fmaf(nay[i], t3.y, fmaf(naz[i], t3.z, t3.w)));
                mgt[i] = fminf(fminf(mgt[i], fminf(d0, d1)), fminf(d2, d3));
            }
        }
        float lN_gt = 0.0f;
        unsigned int gcbits = 0;
#pragma unroll
        for (int i = 0; i < PPT; ++i) {
            float a2 = px[i]*px[i] + py[i]*py[i] + pz[i]*pz[i];
            float dgt = fmaxf(a2 + mgt[i], 0.0f);
            if (sqrtf(dgt) < 0.005f) { lN_gt += 1.0f; gcbits |= (1u << i); }
        }
        gcA[(size_t)r * 256 + tid] = (unsigned char)gcbits;
        atomicAdd(&s_red[0], lN_gt);
        __syncthreads();      // gc bytes + reduction done
        if (tid == 0) {
            __threadfence();  // publish gc bytes before the flag
            __hip_atomic_store(&flags[r], 1u, __ATOMIC_RELEASE, __HIP_MEMORY_SCOPE_AGENT);
            atomicAdd(&acc[5], s_red[0]);
        }
    } else if (blk < GT_BLOCKS + REC_BLOCKS) {
        // ============ REC ROLE: scan + epilogue + local consistency (R0 core) ============
        int r = blk - GT_BLOCKS;
        int b = r >> 2, chunk = r & 3;
        const float4* base = ws4 + (size_t)b * BATCH_F4;
        const float4* rec4p = base + NVP;
        const float4* nrm4p = base + 2 * NVP;
        for (int j = tid; j < NVP; j += 256) s_t[j] = rec4p[j];
        if (tid < 4) s_red[tid] = 0.0f;
        __syncthreads();

        const float* ob = obj + ((size_t)b * N1V + (size_t)chunk * 2048) * 3;
        LOAD_PTS(ob)
        float nax[PPT], nay[PPT], naz[PPT], m[PPT];
        int q[PPT];
#pragma unroll
        for (int i = 0; i < PPT; ++i) {
            nax[i] = -2.0f * px[i]; nay[i] = -2.0f * py[i]; naz[i] = -2.0f * pz[i];
            m[i] = 3.4e38f; q[i] = 0;
        }
        float mp[PPT];
#pragma unroll 1
        for (int jq = 0; jq < SEG1Q; ++jq) {
            int j = 4 * jq;
            float4 t0 = s_t[j], t1 = s_t[j+1], t2 = s_t[j+2], t3 = s_t[j+3];
#pragma unroll
            for (int i = 0; i < PPT; ++i) {
                float d0 = fmaf(nax[i], t0.x, fmaf(nay[i], t0.y, fmaf(naz[i], t0.z, t0.w)));
                float d1 = fmaf(nax[i], t1.x, fmaf(nay[i], t1.y, fmaf(naz[i], t1.z, t1.w)));
                float d2 = fmaf(nax[i], t2.x, fmaf(nay[i], t2.y, fmaf(naz[i], t2.z, t2.w)));
                float d3 = fmaf(nax[i], t3.x, fmaf(nay[i], t3.y, fmaf(naz[i], t3.z, t3.w)));
                float mn = fminf(fminf(fminf(d0, d1), fminf(d2, d3)), m[i]);
                q[i] = (mn < m[i]) ? jq : q[i];
                m[i] = mn;
            }
        }
#pragma unroll
        for (int i = 0; i < PPT; ++i) mp[i] = m[i];   // prior min snapshot
#pragma unroll 1
        for (int jq = SEG1Q; jq < NQ; ++jq) {
            int j = 4 * jq;
            float4 t0 = s_t[j], t1 = s_t[j+1], t2 = s_t[j+2], t3 = s_t[j+3];
#pragma unroll
            for (int i = 0; i < PPT; ++i) {
                float d0 = fmaf(nax[i], t0.x, fmaf(nay[i], t0.y, fmaf(naz[i], t0.z, t0.w)));
                float d1 = fmaf(nax[i], t1.x, fmaf(nay[i], t1.y, fmaf(naz[i], t1.z, t1.w)));
                float d2 = fmaf(nax[i], t2.x, fmaf(nay[i], t2.y, fmaf(naz[i], t2.z, t2.w)));
                float d3 = fmaf(nax[i], t3.x, fmaf(nay[i], t3.y, fmaf(naz[i], t3.z, t3.w)));
                float mn = fminf(fminf(fminf(d0, d1), fminf(d2, d3)), m[i]);
                q[i] = (mn < m[i]) ? jq : q[i];
                m[i] = mn;
            }
        }
        // ---- inline epilogue ----
        float lS_cmap = 0.0f, lN_cmap = 0.0f, lS_pen = 0.0f;
        unsigned int rcbits = 0;
#pragma unroll
        for (int i = 0; i < PPT; ++i) {
            float a2 = px[i]*px[i] + py[i]*py[i] + pz[i]*pz[i];
            float drec = fmaxf(a2 + (m[i]  - BIAS), 0.0f);
            float dpri = fmaxf(a2 + (mp[i] - BIAS), 0.0f);
            bool cm = drec < 1e-4f;
            bool rc = sqrtf(drec) < 0.005f;
            if (cm) { lS_cmap += dpri; lN_cmap += 1.0f; }
            if (rc) rcbits |= (1u << i);
            // winning-quad re-eval from LDS for jstar (bit-identical fma chain)
            int jr = 4 * q[i];
            float4 t0 = s_t[jr], t1 = s_t[jr+1], t2 = s_t[jr+2], t3 = s_t[jr+3];
            float d0 = fmaf(nax[i], t0.x, fmaf(nay[i], t0.y, fmaf(naz[i], t0.z, t0.w)));
            float d1 = fmaf(nax[i], t1.x, fmaf(nay[i], t1.y, fmaf(naz[i], t1.z, t1.w)));
            float d2 = fmaf(nax[i], t2.x, fmaf(nay[i], t2.y, fmaf(naz[i], t2.z, t2.w)));
            float d3 = fmaf(nax[i], t3.x, fmaf(nay[i], t3.y, fmaf(naz[i], t3.z, t3.w)));
            float mmin = fminf(fminf(d0, d1), fminf(d2, d3));
            int off = (d0 == mmin) ? 0 : ((d1 == mmin) ? 1 : ((d2 == mmin) ? 2 : 3));
            int jstar = jr + off;
            float4 tS = s_t[jstar];
            float4 nr = nrm4p[jstar];   // RAW normal sum: only sign of ddot matters
            float ddot = (tS.x - px[i]) * nr.x + (tS.y - py[i]) * nr.y
                       + (tS.z - pz[i]) * nr.z;
            if (ddot > 0.0f) lS_pen += drec;
        }
        atomicAdd(&s_red[0], lS_cmap);
        atomicAdd(&s_red[1], lN_cmap);
        atomicAdd(&s_red[2], lS_pen);
        // ---- consistency: AND in-register rc bits with gt twin's gc byte ----
        spin_wait(&flags[r], tid);    // gt twin finished long ago -> instant
        unsigned int gcb = gcA[(size_t)r * 256 + tid];
        float lcons = (float)__popc(rcbits & gcb);
        atomicAdd(&s_red[3], lcons);
        __syncthreads();
        if (tid == 0) atomicAdd(&acc[3], s_red[0]);
        if (tid == 1) atomicAdd(&acc[4], s_red[1]);
        if (tid == 2) atomicAdd(&acc[7], s_red[2]);
        if (tid == 3) atomicAdd(&acc[6], s_red[3]);
    } else {
        // ============ CHAMFER ROLE (R0 verbatim) ============
        int c   = blk - (GT_BLOCKS + REC_BLOCKS);
        int b   = c >> 1;
        int dir = c & 1;           // 0: rec->gt, 1: gt->rec
        const float4* base = ws4 + (size_t)b * BATCH_F4;
        const float4* srcv = dir ? base : (base + NVP);   // gt4 : rec4p
        const float4* tgtv = dir ? (base + NVP) : base;   // rec4p : gt4
        for (int j = tid; j < NVP; j += 256) s_t[j] = tgtv[j];
        if (tid == 0) s_red[0] = 0.0f;
        __syncthreads();

        const int CPT = 4;
        float nax[CPT], nay[CPT], naz[CPT], a2[CPT], m[CPT];
        bool valid[CPT];
#pragma unroll
        for (int k = 0; k < CPT; ++k) {
            int p = tid + 256 * k;
            valid[k] = (p < NV);
            float4 s = srcv[valid[k] ? p : 0];
            nax[k] = -2.0f * s.x; nay[k] = -2.0f * s.y; naz[k] = -2.0f * s.z;
            a2[k] = s.w;                  // one of src/tgt carries +BIAS
            m[k] = 3.4e38f;
        }
#pragma unroll 1
        for (int j = 0; j < NVP; j += 4) {
            float4 t0 = s_t[j], t1 = s_t[j+1], t2 = s_t[j+2], t3 = s_t[j+3];
#pragma unroll
            for (int k = 0; k < CPT; ++k) {
                float d0 = fmaf(nax[k], t0.x, fmaf(nay[k], t0.y, fmaf(naz[k], t0.z, t0.w)));
                float d1 = fmaf(nax[k], t1.x, fmaf(nay[k], t1.y, fmaf(naz[k], t1.z, t1.w)));
                float d2 = fmaf(nax[k], t2.x, fmaf(nay[k], t2.y, fmaf(naz[k], t2.z, t2.w)));
                float d3 = fmaf(nax[k], t3.x, fmaf(nay[k], t3.y, fmaf(naz[k], t3.z, t3.w)));
                m[k] = fminf(fminf(m[k], fminf(d0, d1)), fminf(d2, d3));
            }
        }
        float local = 0.0f;
#pragma unroll
        for (int k = 0; k < CPT; ++k)
            if (valid[k]) local += fmaxf(a2[k] + m[k] - BIAS, 0.0f);
        atomicAdd(&s_red[0], local);
        __syncthreads();
        if (tid == 0) atomicAdd(&acc[2], s_red[0]);
    }

    // ============ TICKET + FORMULA (last block; ~7 loads, no popcount) ============
    __syncthreads();   // this block's global atomics retired
    if (tid == 0) {
        __threadfence();                 // release
        s_tk = atomicAdd((unsigned int*)&acc[15], 1u);
    }
    __syncthreads();
    if (s_tk == NROLE_BLOCKS - 1 && tid == 0) {
        __threadfence();                 // acquire
        const float fB = 64.0f;
        float a2v = __hip_atomic_load(&acc[2], __ATOMIC_RELAXED, __HIP_MEMORY_SCOPE_AGENT);
        float a3  = __hip_atomic_load(&acc[3], __ATOMIC_RELAXED, __HIP_MEMORY_SCOPE_AGENT);
        float a4  = __hip_atomic_load(&acc[4], __ATOMIC_RELAXED, __HIP_MEMORY_SCOPE_AGENT);
        float a5  = __hip_atomic_load(&acc[5], __ATOMIC_RELAXED, __HIP_MEMORY_SCOPE_AGENT);
        float a6  = __hip_atomic_load(&acc[6], __ATOMIC_RELAXED, __HIP_MEMORY_SCOPE_AGENT);
        float a7  = __hip_atomic_load(&acc[7], __ATOMIC_RELAXED, __HIP_MEMORY_SCOPE_AGENT);
        float a8  = __hip_atomic_load(&acc[8], __ATOMIC_RELAXED, __HIP_MEMORY_SCOPE_AGENT);
        float a9  = __hip_atomic_load(&acc[9], __ATOMIC_RELAXED, __HIP_MEMORY_SCOPE_AGENT);
        float param_loss  = a8 / fB;
        float KLD         = -0.5f * a9 / fB * 10.0f;
        float recon_loss  = a2v / fB;
        float cmap_loss   = 3000.0f * a3 / (fB * a4);
        float consistency = -5.0f * a6 / (a5 + 0.0001f);
        float penetr      = 100.0f * a7 / fB;
        out[0] = (recon_loss + KLD) + 0.1f * param_loss + 1000.0f * cmap_loss
               + 10.0f * consistency + 10.0f * penetr;
    }
}

extern "C" void kernel_launch(void* const* d_in, const int* in_sizes, int n_in,
                              void* d_out, int out_size, void* d_ws, size_t ws_size,
                              hipStream_t stream) {
    (void)in_sizes; (void)n_in; (void)out_size; (void)ws_size;
    const float* obj     = (const float*)d_in[0];
    const float* recon   = (const float*)d_in[1];
    const float* gt      = (const float*)d_in[2];
    const float* mean    = (const float*)d_in[3];
    const float* log_var = (const float*)d_in[4];
    const float* rp      = (const float*)d_in[5];
    const float* xp      = (const float*)d_in[6];
    const int*   faces   = (const int*)d_in[7];
    float* wsf = (float*)d_ws;
    float4* ws4 = (float4*)d_ws;
    float* acc = wsf + ACC_OFF;
    unsigned int* flags = (unsigned int*)(wsf + FLAGS_OFF);
    unsigned char* gcA  = (unsigned char*)(wsf + GC_OFF);
    float* out = (float*)d_out;

    k_prep <<<PREP_BLOCKS,  256, 0, stream>>>(recon, gt, faces, mean, log_var,
                                              rp, xp, ws4, acc, flags);
    k_fused<<<NROLE_BLOCKS, 256, 0, stream>>>(obj, ws4, acc, flags, gcA, out);
}

// Round 9
// 167.421 us; speedup vs baseline: 1.3516x; 1.1330x over previous
//
#include <hip/hip_runtime.h>
#include <math.h>

// Problem constants (from reference setup_inputs)
#define NB     64      // batch
#define N1V    8192    // obj points per batch
#define NPTS   (NB * N1V)
#define NV     778     // recon / gt verts
#define NVP    780     // padded to multiple of 4
#define NQ     195     // target quads
#define SEG1Q  51      // first 51 quads = 204 permuted targets = PRIOR set
#define NFACE  1538
#define NZ     64
#define NPAR   61
#define NPRIOR 204
#define PPT    8       // obj points per thread (rec/gt roles)
#define BIAS   0.0625f // 2|a||t| <= 0.06 < BIAS -> biased rec partials stay >= 0

// Single kernel, 4 roles. Scan blocks transform raw inputs inline (no staging
// dependency). Only normals need cross-point reduction -> NRM blocks + flag.
#define GT_BLOCKS  256                 // [0,256): (batch, chunk) gt min + gc bits
#define REC_BLOCKS 256                 // [256,512): rec argmin + epilogue
#define CH_BLOCKS  128                 // [512,640): chamfer (batch, dir)
#define NRM_BLOCKS 64                  // [640,704): per-batch normals -> ws
#define REC_BASE GT_BLOCKS
#define CH_BASE  (REC_BASE + REC_BLOCKS)
#define NRM_BASE (CH_BASE + CH_BLOCKS)
#define NBLOCKS  (NRM_BASE + NRM_BLOCKS)   // 704
// Deadlock safety: all 704 must be co-resident. LDS 18.7KB -> 8 blocks/CU ->
// capacity 2048 >> 704. (Even VGPR 128 -> 4/CU = 1024, still fine.)

// ws float layout:
//   [0, NB*NVP*4)  nrm4p[NB][NVP] float4: RAW face-normal sums, PERMUTED
//   acc[16]        at ACC_OFF: 2 chamfer, 3 S_cmap, 4 N_cmap, 5 N_gt,
//                  6 N_cons, 7 S_pen, 8 param, 9 kld, 15 ticket
//   flags[320]     [0,256) per gt-chunk gc release; [256,320) per-batch nrm
//   gcA            uchar[NPTS/8] gt-cmap bits
#define ACC_OFF   (NB * NVP * 4)
#define FLAGS_OFF (ACC_OFF + 16)
#define NFLAGS    320
#define GC_OFF    (FLAGS_OFF + NFLAGS)

// ---- compile-time prior permutation (pure function of the static index list) ----
static constexpr int PRIOR_LIST[NPRIOR] = {
  697,698,699,700,712,713,714,715,737,738,739,740,741,743,744,745,746,748,749,750,
  753,754,755,756,757,758,759,760,761,762,763,764,765,766,767,768,
  46,47,48,49,164,165,166,167,194,195,223,237,238,280,281,298,301,317,320,323,
  324,325,326,327,328,329,330,331,332,333,340,341,342,343,344,345,346,347,348,349,
  350,351,352,353,354,355,
  356,357,358,359,375,376,386,387,396,397,402,403,413,429,433,434,435,436,437,438,
  439,440,441,442,443,444,452,453,454,455,456,459,460,461,462,463,464,465,466,467,
  468,469,470,471,484,485,486,496,497,506,507,513,514,524,545,546,547,548,549,550,
  551,552,553,555,563,564,565,566,567,570,572,573,574,575,576,577,578,
  580,581,582,583,600,601,602,614,615,624,625,630,631,641,663,664,665,666,667,668,
  670,672,680,681,682,683,684,686,687,688,689,690,691,692,693,694,695,
  73,96,98,99,772,774,775,777
};

struct PermT { unsigned short v[NV]; };
static constexpr PermT make_perm() {
    PermT t{};
    bool mem[NV] = {};
    for (int i = 0; i < NPRIOR; ++i) mem[PRIOR_LIST[i]] = true;
    int a = 0, b = NPRIOR;
    for (int j = 0; j < NV; ++j) {
        if (mem[j]) t.v[a++] = (unsigned short)j;
        else        t.v[b++] = (unsigned short)j;
    }
    return t;
}
__device__ __constant__ PermT c_perm = make_perm();

struct ScanSh { float4 t[NVP]; float red[4]; };
struct NrmSh  { float x[NV], y[NV], z[NV], vnx[NV], vny[NV], vnz[NV]; };
union ShU { ScanSh scan; NrmSh nrm; };

#define LOAD_PTS(ob)                                                          \
    const float4* ob4 = (const float4*)((ob) + (size_t)tid * 24);             \
    float4 q0 = ob4[0], q1 = ob4[1], q2 = ob4[2],                             \
           q3 = ob4[3], q4 = ob4[4], q5 = ob4[5];                             \
    float px[PPT], py[PPT], pz[PPT];                                          \
    px[0]=q0.x; py[0]=q0.y; pz[0]=q0.z;  px[1]=q0.w; py[1]=q1.x; pz[1]=q1.y;  \
    px[2]=q1.z; py[2]=q1.w; pz[2]=q2.x;  px[3]=q2.y; py[3]=q2.z; pz[3]=q2.w;  \
    px[4]=q3.x; py[4]=q3.y; pz[4]=q3.z;  px[5]=q3.w; py[5]=q4.x; pz[5]=q4.y;  \
    px[6]=q4.z; py[6]=q4.w; pz[6]=q5.x;  px[7]=q5.y; py[7]=q5.z; pz[7]=q5.w;

__device__ __forceinline__ void spin_wait(unsigned int* f, int tid) {
    if (tid == 0) {
        while (__hip_atomic_load(f, __ATOMIC_ACQUIRE, __HIP_MEMORY_SCOPE_AGENT) == 0u)
            __builtin_amdgcn_s_sleep(2);
    }
    __syncthreads();   // tid0's acquire + barrier orders subsequent reads
}

__global__ __launch_bounds__(256) void k_all(
        const float* __restrict__ obj,   const float* __restrict__ recon,
        const float* __restrict__ gt,    const int*   __restrict__ faces,
        const float* __restrict__ mean,  const float* __restrict__ log_var,
        const float* __restrict__ rp,    const float* __restrict__ xp,
        float4* __restrict__ ws4,        float* __restrict__ acc,
        unsigned int* __restrict__ flags, unsigned char* __restrict__ gcA,
        float* __restrict__ out) {
    __shared__ ShU sh;
    __shared__ unsigned int s_tk;
    __shared__ float s_pk[2];
    int tid = threadIdx.x;
    int blk = blockIdx.x;

    if (blk < GT_BLOCKS) {
        // ============ GT ROLE: inline transform + min scan + gc bits + release ============
        int r = blk, b = r >> 2, chunk = r & 3;
        const float* gb = gt + (size_t)b * NV * 3;
        float4* s_t = sh.scan.t;
        for (int j = tid; j < NVP; j += 256) {
            if (j < NV) {
                float x = gb[3*j], y = gb[3*j+1], z = gb[3*j+2];
                s_t[j] = make_float4(x, y, z, x*x + y*y + z*z);
            } else s_t[j] = make_float4(0.f, 0.f, 0.f, 1e30f);
        }
        if (tid == 0) sh.scan.red[0] = 0.0f;
        __syncthreads();

        const float* ob = obj + ((size_t)b * N1V + (size_t)chunk * 2048) * 3;
        LOAD_PTS(ob)
        float nax[PPT], nay[PPT], naz[PPT], mgt[PPT];
#pragma unroll
        for (int i = 0; i < PPT; ++i) {
            nax[i] = -2.0f * px[i]; nay[i] = -2.0f * py[i]; naz[i] = -2.0f * pz[i];
            mgt[i] = 3.4e38f;
        }
#pragma unroll 1
        for (int jq = 0; jq < NQ; ++jq) {
            int j = 4 * jq;
            float4 t0 = s_t[j], t1 = s_t[j+1], t2 = s_t[j+2], t3 = s_t[j+3];
#pragma unroll
            for (int i = 0; i < PPT; ++i) {
                float d0 = fmaf(nax[i], t0.x, fmaf(nay[i], t0.y, fmaf(naz[i], t0.z, t0.w)));
                float d1 = fmaf(nax[i], t1.x, fmaf(nay[i], t1.y, fmaf(naz[i], t1.z, t1.w)));
                float d2 = fmaf(nax[i], t2.x, fmaf(nay[i], t2.y, fmaf(naz[i], t2.z, t2.w)));
                float d3 = fmaf(nax[i], t3.x, fmaf(nay[i], t3.y, fmaf(naz[i], t3.z, t3.w)));
                mgt[i] = fminf(fminf(mgt[i], fminf(d0, d1)), fminf(d2, d3));
            }
        }
        float lN_gt = 0.0f;
        unsigned int gcbits = 0;
#pragma unroll
        for (int i = 0; i < PPT; ++i) {
            float a2 = px[i]*px[i] + py[i]*py[i] + pz[i]*pz[i];
            float dgt = fmaxf(a2 + mgt[i], 0.0f);
            if (sqrtf(dgt) < 0.005f) { lN_gt += 1.0f; gcbits |= (1u << i); }
        }
        gcA[(size_t)r * 256 + tid] = (unsigned char)gcbits;
        atomicAdd(&sh.scan.red[0], lN_gt);
        __syncthreads();      // gc bytes + reduction done
        if (tid == 0) {
            __threadfence();  // publish gc BYTES (non-atomic) before the flag
            __hip_atomic_store(&flags[r], 1u, __ATOMIC_RELEASE, __HIP_MEMORY_SCOPE_AGENT);
            atomicAdd(&acc[5], sh.scan.red[0]);
        }
    } else if (blk < CH_BASE) {
        // ============ REC ROLE: inline perm staging + scan + split epilogue ============
        int r = blk - REC_BASE, b = r >> 2, chunk = r & 3;
        const float* rb = recon + (size_t)b * NV * 3;
        float4* s_t = sh.scan.t;
        for (int j = tid; j < NVP; j += 256) {
            if (j < NV) {
                int src = c_perm.v[j];
                float x = rb[3*src], y = rb[3*src+1], z = rb[3*src+2];
                s_t[j] = make_float4(x, y, z, x*x + y*y + z*z + BIAS);
            } else s_t[j] = make_float4(0.f, 0.f, 0.f, 1e30f);
        }
        if (tid < 4) sh.scan.red[tid] = 0.0f;
        __syncthreads();

        const float* ob = obj + ((size_t)b * N1V + (size_t)chunk * 2048) * 3;
        LOAD_PTS(ob)
        float nax[PPT], nay[PPT], naz[PPT], m[PPT];
        int q[PPT];
#pragma unroll
        for (int i = 0; i < PPT; ++i) {
            nax[i] = -2.0f * px[i]; nay[i] = -2.0f * py[i]; naz[i] = -2.0f * pz[i];
            m[i] = 3.4e38f; q[i] = 0;
        }
        float mp[PPT];
#pragma unroll 1
        for (int jq = 0; jq < SEG1Q; ++jq) {
            int j = 4 * jq;
            float4 t0 = s_t[j], t1 = s_t[j+1], t2 = s_t[j+2], t3 = s_t[j+3];
#pragma unroll
            for (int i = 0; i < PPT; ++i) {
                float d0 = fmaf(nax[i], t0.x, fmaf(nay[i], t0.y, fmaf(naz[i], t0.z, t0.w)));
                float d1 = fmaf(nax[i], t1.x, fmaf(nay[i], t1.y, fmaf(naz[i], t1.z, t1.w)));
                float d2 = fmaf(nax[i], t2.x, fmaf(nay[i], t2.y, fmaf(naz[i], t2.z, t2.w)));
                float d3 = fmaf(nax[i], t3.x, fmaf(nay[i], t3.y, fmaf(naz[i], t3.z, t3.w)));
                float mn = fminf(fminf(fminf(d0, d1), fminf(d2, d3)), m[i]);
                q[i] = (mn < m[i]) ? jq : q[i];
                m[i] = mn;
            }
        }
#pragma unroll
        for (int i = 0; i < PPT; ++i) mp[i] = m[i];   // prior min snapshot
#pragma unroll 1
        for (int jq = SEG1Q; jq < NQ; ++jq) {
            int j = 4 * jq;
            float4 t0 = s_t[j], t1 = s_t[j+1], t2 = s_t[j+2], t3 = s_t[j+3];
#pragma unroll
            for (int i = 0; i < PPT; ++i) {
                float d0 = fmaf(nax[i], t0.x, fmaf(nay[i], t0.y, fmaf(naz[i], t0.z, t0.w)));
                float d1 = fmaf(nax[i], t1.x, fmaf(nay[i], t1.y, fmaf(naz[i], t1.z, t1.w)));
                float d2 = fmaf(nax[i], t2.x, fmaf(nay[i], t2.y, fmaf(naz[i], t2.z, t2.w)));
                float d3 = fmaf(nax[i], t3.x, fmaf(nay[i], t3.y, fmaf(naz[i], t3.z, t3.w)));
                float mn = fminf(fminf(fminf(d0, d1), fminf(d2, d3)), m[i]);
                q[i] = (mn < m[i]) ? jq : q[i];
                m[i] = mn;
            }
        }
        // ---- epilogue pass 1: everything except the normal gather ----
        float lS_cmap = 0.0f, lN_cmap = 0.0f;
        unsigned int rcbits = 0;
        int js[PPT]; float drecs[PPT];
#pragma unroll
        for (int i = 0; i < PPT; ++i) {
            float a2 = px[i]*px[i] + py[i]*py[i] + pz[i]*pz[i];
            float drec = fmaxf(a2 + (m[i]  - BIAS), 0.0f);
            float dpri = fmaxf(a2 + (mp[i] - BIAS), 0.0f);
            bool cm = drec < 1e-4f;
            bool rc = sqrtf(drec) < 0.005f;
            if (cm) { lS_cmap += dpri; lN_cmap += 1.0f; }
            if (rc) rcbits |= (1u << i);
            // winning-quad re-eval from LDS for jstar (bit-identical fma chain)
            int jr = 4 * q[i];
            float4 t0 = s_t[jr], t1 = s_t[jr+1], t2 = s_t[jr+2], t3 = s_t[jr+3];
            float d0 = fmaf(nax[i], t0.x, fmaf(nay[i], t0.y, fmaf(naz[i], t0.z, t0.w)));
            float d1 = fmaf(nax[i], t1.x, fmaf(nay[i], t1.y, fmaf(naz[i], t1.z, t1.w)));
            float d2 = fmaf(nax[i], t2.x, fmaf(nay[i], t2.y, fmaf(naz[i], t2.z, t2.w)));
            float d3 = fmaf(nax[i], t3.x, fmaf(nay[i], t3.y, fmaf(naz[i], t3.z, t3.w)));
            float mmin = fminf(fminf(d0, d1), fminf(d2, d3));
            int off = (d0 == mmin) ? 0 : ((d1 == mmin) ? 1 : ((d2 == mmin) ? 2 : 3));
            js[i] = jr + off;
            drecs[i] = drec;
        }
        atomicAdd(&sh.scan.red[0], lS_cmap);
        atomicAdd(&sh.scan.red[1], lN_cmap);
        // ---- wait for normals (done at ~8us) and gt twin (done before us) ----
        spin_wait(&flags[256 + b], tid);   // nrm4p published
        spin_wait(&flags[r], tid);         // gc bytes published
        const float4* nrm4p = ws4 + (size_t)b * NVP;
        float lS_pen = 0.0f;
#pragma unroll
        for (int i = 0; i < PPT; ++i) {
            float4 tS = s_t[js[i]];
            float4 nr = nrm4p[js[i]];   // RAW normal sum: only sign of ddot matters
            float ddot = (tS.x - px[i]) * nr.x + (tS.y - py[i]) * nr.y
                       + (tS.z - pz[i]) * nr.z;
            if (ddot > 0.0f) lS_pen += drecs[i];
        }
        unsigned int gcb = gcA[(size_t)r * 256 + tid];
        float lcons = (float)__popc(rcbits & gcb);
        atomicAdd(&sh.scan.red[2], lS_pen);
        atomicAdd(&sh.scan.red[3], lcons);
        __syncthreads();
        if (tid == 0) atomicAdd(&acc[3], sh.scan.red[0]);
        if (tid == 1) atomicAdd(&acc[4], sh.scan.red[1]);
        if (tid == 2) atomicAdd(&acc[7], sh.scan.red[2]);
        if (tid == 3) atomicAdd(&acc[6], sh.scan.red[3]);
    } else if (blk < NRM_BASE) {
        // ============ CHAMFER ROLE: inline transforms, original order ============
        int c   = blk - CH_BASE;
        int b   = c >> 1;
        int dir = c & 1;           // 0: rec->gt, 1: gt->rec
        const float* rb = recon + (size_t)b * NV * 3;
        const float* gb = gt    + (size_t)b * NV * 3;
        const float* tb = dir ? rb : gb;   // target side (rec carries +BIAS)
        const float* sb = dir ? gb : rb;   // source side
        float4* s_t = sh.scan.t;
        for (int j = tid; j < NVP; j += 256) {
            if (j < NV) {
                float x = tb[3*j], y = tb[3*j+1], z = tb[3*j+2];
                float w = x*x + y*y + z*z;
                if (dir) w += BIAS;        // rec side carries BIAS
                s_t[j] = make_float4(x, y, z, w);
            } else s_t[j] = make_float4(0.f, 0.f, 0.f, 1e30f);
        }
        if (tid == 0) sh.scan.red[0] = 0.0f;
        __syncthreads();

        const int CPT = 4;
        float nax[CPT], nay[CPT], naz[CPT], a2[CPT], m[CPT];
        bool valid[CPT];
#pragma unroll
        for (int k = 0; k < CPT; ++k) {
            int p = tid + 256 * k;
            valid[k] = (p < NV);
            int pp = valid[k] ? p : 0;
            float x = sb[3*pp], y = sb[3*pp+1], z = sb[3*pp+2];
            float w = x*x + y*y + z*z;
            if (!dir) w += BIAS;           // rec side carries BIAS
            nax[k] = -2.0f * x; nay[k] = -2.0f * y; naz[k] = -2.0f * z;
            a2[k] = w;
            m[k] = 3.4e38f;
        }
#pragma unroll 1
        for (int j = 0; j < NVP; j += 4) {
            float4 t0 = s_t[j], t1 = s_t[j+1], t2 = s_t[j+2], t3 = s_t[j+3];
#pragma unroll
            for (int k = 0; k < CPT; ++k) {
                float d0 = fmaf(nax[k], t0.x, fmaf(nay[k], t0.y, fmaf(naz[k], t0.z, t0.w)));
                float d1 = fmaf(nax[k], t1.x, fmaf(nay[k], t1.y, fmaf(naz[k], t1.z, t1.w)));
                float d2 = fmaf(nax[k], t2.x, fmaf(nay[k], t2.y, fmaf(naz[k], t2.z, t2.w)));
                float d3 = fmaf(nax[k], t3.x, fmaf(nay[k], t3.y, fmaf(naz[k], t3.z, t3.w)));
                m[k] = fminf(fminf(m[k], fminf(d0, d1)), fminf(d2, d3));
            }
        }
        float local = 0.0f;
#pragma unroll
        for (int k = 0; k < CPT; ++k)
            if (valid[k]) local += fmaxf(a2[k] + m[k] - BIAS, 0.0f);
        atomicAdd(&sh.scan.red[0], local);
        __syncthreads();
        if (tid == 0) atomicAdd(&acc[2], sh.scan.red[0]);
    } else {
        // ============ NRM ROLE: per-batch raw normal sums -> ws + flag ============
        int b = blk - NRM_BASE;
        const float* rb = recon + (size_t)b * NV * 3;
        for (int j = tid; j < NV; j += 256) {
            sh.nrm.x[j] = rb[3*j]; sh.nrm.y[j] = rb[3*j+1]; sh.nrm.z[j] = rb[3*j+2];
            sh.nrm.vnx[j] = 0.0f; sh.nrm.vny[j] = 0.0f; sh.nrm.vnz[j] = 0.0f;
        }
        __syncthreads();
        for (int f = tid; f < NFACE; f += 256) {
            int i0 = faces[3*f], i1 = faces[3*f+1], i2 = faces[3*f+2];
            float p0x = sh.nrm.x[i0], p0y = sh.nrm.y[i0], p0z = sh.nrm.z[i0];
            float e1x = sh.nrm.x[i1] - p0x, e1y = sh.nrm.y[i1] - p0y, e1z = sh.nrm.z[i1] - p0z;
            float e2x = sh.nrm.x[i2] - p0x, e2y = sh.nrm.y[i2] - p0y, e2z = sh.nrm.z[i2] - p0z;
            float fx = e1y * e2z - e1z * e2y;
            float fy = e1z * e2x - e1x * e2z;
            float fz = e1x * e2y - e1y * e2x;
            atomicAdd(&sh.nrm.vnx[i0], fx); atomicAdd(&sh.nrm.vny[i0], fy); atomicAdd(&sh.nrm.vnz[i0], fz);
            atomicAdd(&sh.nrm.vnx[i1], fx); atomicAdd(&sh.nrm.vny[i1], fy); atomicAdd(&sh.nrm.vnz[i1], fz);
            atomicAdd(&sh.nrm.vnx[i2], fx); atomicAdd(&sh.nrm.vny[i2], fy); atomicAdd(&sh.nrm.vnz[i2], fz);
        }
        __syncthreads();
        float4* nrm4p = ws4 + (size_t)b * NVP;
        for (int j = tid; j < NVP; j += 256) {
            if (j < NV) {
                int src = c_perm.v[j];
                nrm4p[j] = make_float4(sh.nrm.vnx[src], sh.nrm.vny[src], sh.nrm.vnz[src], 0.0f);
            } else nrm4p[j] = make_float4(0.f, 0.f, 1.f, 0.0f);
        }
        __syncthreads();   // all nrm4p stores issued block-wide
        if (tid == 0) {
            __threadfence();  // publish nrm4p BYTES (non-atomic) before the flag
            __hip_atomic_store(&flags[256 + b], 1u, __ATOMIC_RELEASE, __HIP_MEMORY_SCOPE_AGENT);
        }
        if (b == 0) {
            // ---- param + KLD on the side (long before any consumer) ----
            if (tid < 2) s_pk[tid] = 0.0f;
            __syncthreads();
            float s_param = 0.0f, s_kld = 0.0f;
            for (int i = tid; i < NB * NPAR; i += 256) {
                float d = rp[i] - xp[i];
                s_param += d * d;
            }
            for (int i = tid; i < NB * NZ; i += 256) {
                float mv = mean[i], lv = log_var[i];
                s_kld += 1.0f + lv - mv * mv - expf(lv);
            }
            atomicAdd(&s_pk[0], s_param);
            atomicAdd(&s_pk[1], s_kld);
            __syncthreads();
            if (tid == 0) { atomicAdd(&acc[8], s_pk[0]); atomicAdd(&acc[9], s_pk[1]); }
        }
    }

    // ============ TICKET + FORMULA (vmcnt-ordered; no per-block L2 writeback) ============
    __syncthreads();   // block's global atomics all issued
    if (tid == 0) {
        // device-scope atomics complete at the coherence point; vmcnt(0) orders
        // this wave's acc-adds before the ticket-add (G12: atomics are device-scope)
        asm volatile("s_waitcnt vmcnt(0)" ::: "memory");
        s_tk = atomicAdd((unsigned int*)&acc[15], 1u);
    }
    __syncthreads();
    if (s_tk == NBLOCKS - 1 && tid == 0) {
        __threadfence();                 // acquire (single block, negligible)
        const float fB = 64.0f;
        float a2v = __hip_atomic_load(&acc[2], __ATOMIC_RELAXED, __HIP_MEMORY_SCOPE_AGENT);
        float a3  = __hip_atomic_load(&acc[3], __ATOMIC_RELAXED, __HIP_MEMORY_SCOPE_AGENT);
        float a4  = __hip_atomic_load(&acc[4], __ATOMIC_RELAXED, __HIP_MEMORY_SCOPE_AGENT);
        float a5  = __hip_atomic_load(&acc[5], __ATOMIC_RELAXED, __HIP_MEMORY_SCOPE_AGENT);
        float a6  = __hip_atomic_load(&acc[6], __ATOMIC_RELAXED, __HIP_MEMORY_SCOPE_AGENT);
        float a7  = __hip_atomic_load(&acc[7], __ATOMIC_RELAXED, __HIP_MEMORY_SCOPE_AGENT);
        float a8  = __hip_atomic_load(&acc[8], __ATOMIC_RELAXED, __HIP_MEMORY_SCOPE_AGENT);
        float a9  = __hip_atomic_load(&acc[9], __ATOMIC_RELAXED, __HIP_MEMORY_SCOPE_AGENT);
        float param_loss  = a8 / fB;
        float KLD         = -0.5f * a9 / fB * 10.0f;
        float recon_loss  = a2v / fB;
        float cmap_loss   = 3000.0f * a3 / (fB * a4);
        float consistency = -5.0f * a6 / (a5 + 0.0001f);
        float penetr      = 100.0f * a7 / fB;
        out[0] = (recon_loss + KLD) + 0.1f * param_loss + 1000.0f * cmap_loss
               + 10.0f * consistency + 10.0f * penetr;
    }
}

extern "C" void kernel_launch(void* const* d_in, const int* in_sizes, int n_in,
                              void* d_out, int out_size, void* d_ws, size_t ws_size,
                              hipStream_t stream) {
    (void)in_sizes; (void)n_in; (void)out_size; (void)ws_size;
    const float* obj     = (const float*)d_in[0];
    const float* recon   = (const float*)d_in[1];
    const float* gt      = (const float*)d_in[2];
    const float* mean    = (const float*)d_in[3];
    const float* log_var = (const float*)d_in[4];
    const float* rp      = (const float*)d_in[5];
    const float* xp      = (const float*)d_in[6];
    const int*   faces   = (const int*)d_in[7];
    float* wsf = (float*)d_ws;
    float4* ws4 = (float4*)d_ws;
    float* acc = wsf + ACC_OFF;
    unsigned int* flags = (unsigned int*)(wsf + FLAGS_OFF);
    unsigned char* gcA  = (unsigned char*)(wsf + GC_OFF);
    float* out = (float*)d_out;

    hipMemsetAsync(acc, 0, (16 + NFLAGS) * sizeof(float), stream);
    k_all<<<NBLOCKS, 256, 0, stream>>>(obj, recon, gt, faces, mean, log_var,
                                       rp, xp, ws4, acc, flags, gcA, out);
}